// Round 4
// baseline (207.922 us; speedup 1.0000x reference)
//
#include <hip/hip_runtime.h>
#include <hip/hip_bf16.h>

#define T_LEN 1000
#define B_N 8
#define IN_CH 80
#define CONV_CH 256
#define CCEP_N 222

typedef short s8v __attribute__((ext_vector_type(8)));    // 8 bf16 (4 VGPRs)
typedef float f16v __attribute__((ext_vector_type(16)));  // MFMA 32x32 acc

#define TWO_PI 6.28318530717958647692f

// ===================== fused prep kernel (weights + tables) ===================
// Conv1-3 weights transposed to [s][o] with s = i*3+k: Wt[(i*3+k)*256 + o].
// Lane=time conv kernel reads these as wave-uniform scalar (SMEM) loads.
// blocks [0,240): W1; [240,336): W2; [336,432): W3; [432,1200): W4 chunks;
// [1200,1206): twiddle (1020 float2) + window (512).
__global__ __launch_bounds__(256) void k_prep(
    const float* __restrict__ W1, const float* __restrict__ W2,
    const float* __restrict__ W3, const float* __restrict__ W4,
    float* __restrict__ Wt1, float* __restrict__ Wt2, float* __restrict__ Wt3,
    __hip_bfloat16* __restrict__ Wc, float2* __restrict__ twTab,
    float* __restrict__ winTab) {
  const int bid = blockIdx.x, tid = threadIdx.x;
  if (bid < 240) {
    int e = bid * 256 + tid;                 // 61440 = 240*256
    int o = e & 255, s = e >> 8;             // s = i*3+k (0..239)
    Wt1[e] = W1[o * 240 + s];                // W1 is (256, 80, 3)
  } else if (bid < 336) {
    int e = (bid - 240) * 256 + tid;         // 24576 = 96*256
    int o = e & 255, s = e >> 8;             // s = i*3+k (0..95)
    Wt2[e] = W2[o * 96 + s];                 // W2 is (256, 32, 3)
  } else if (bid < 432) {
    int e = (bid - 336) * 256 + tid;
    int o = e & 255, s = e >> 8;
    Wt3[e] = W3[o * 96 + s];
  } else if (bid < 1200) {
    int e = (bid - 432) * 256 + tid;         // 196608
    int kloc = e & 31, n = (e >> 5) & 255, chg = e >> 13;
    int kp = chg * 32 + kloc;
    int kappa = kp >> 8, i = kp & 255;
    float v = 0.f;
    if (n < CCEP_N) {
      float invq = 1.f / (float)((n < 111) ? (111 - n) : (n - 110));
      v = W4[n * 768 + i * 3 + kappa] * invq;
    }
    Wc[e] = __float2bfloat16(v);
  } else {
    int e = (bid - 1200) * 256 + tid;        // 0..1535
    if (e < 1020) {
      int Q, off;
      if (e < 768)       { Q = 256; off = 0; }
      else if (e < 960)  { Q = 64;  off = 768; }
      else if (e < 1008) { Q = 16;  off = 960; }
      else               { Q = 4;   off = 1008; }
      int rem = e - off;
      int r = rem / Q, pos = rem - r * Q;
      float ang = (TWO_PI * (float)((r + 1) * pos)) / (float)(4 * Q);
      float s, c;
      sincosf(ang, &s, &c);
      twTab[e] = make_float2(c, s);
    } else if (e < 1532) {
      int n = e - 1020;
      winTab[n] = (0.5f - 0.5f * cosf(TWO_PI * (float)n / 512.f)) * (1.f / 1024.f);
    }
  }
}

// ===== conv stack, lane = time =================================================
// Block: 256 thr = 4 waves; covers TTILE=60 output t's x 64 output channels
// (blockIdx.z*64). Wave w owns 16 channels (2 passes of 8), lane l owns one
// time position. Activations in LDS channel-major: lane reads are stride-1
// (conflict-free, 256B useful/instr). Weights wave-uniform -> SMEM s_load via
// readfirstlane'd base, with explicit next-i prefetch rotation (cw/nw).
// Grouped convs: 64-ch block is closed under the 32-ch groups.
#define TTILE 60
#define XP 66     // xs pitch: t = t0-3 .. t0+62 (66)
#define HP 66     // h1s/h2s pitch (64 written, +2 OOB-read headroom)

template <int NI, int PITCH>
__device__ __forceinline__ void conv8(const float* __restrict__ act,
    const float* __restrict__ wb, int l, float* __restrict__ acc) {
  float cw[24], nw[24];
#pragma unroll
  for (int q = 0; q < 24; ++q) cw[q] = wb[(q >> 3) * 256 + (q & 7)];
  for (int i = 0; i < NI; ++i) {
    const float* wn = wb + min(i + 1, NI - 1) * 768;
#pragma unroll
    for (int q = 0; q < 24; ++q) nw[q] = wn[(q >> 3) * 256 + (q & 7)];
    float a0 = act[i * PITCH + l];
    float a1 = act[i * PITCH + l + 1];
    float a2 = act[i * PITCH + l + 2];
#pragma unroll
    for (int oc = 0; oc < 8; ++oc)
      acc[oc] = fmaf(a0, cw[oc], fmaf(a1, cw[8 + oc], fmaf(a2, cw[16 + oc], acc[oc])));
#pragma unroll
    for (int q = 0; q < 24; ++q) cw[q] = nw[q];
  }
}

__global__ __launch_bounds__(256) void k_convall(const float* __restrict__ x,
    const float* __restrict__ Wt1, const float* __restrict__ b1,
    const float* __restrict__ Wt2, const float* __restrict__ b2,
    const float* __restrict__ Wt3, const float* __restrict__ b3,
    __hip_bfloat16* __restrict__ out) {
  const int t0 = blockIdx.x * TTILE;
  const int b  = blockIdx.y;
  const int O0 = blockIdx.z * 64;
  const int tid = threadIdx.x;
  const int l = tid & 63;
  const int w = tid >> 6;
  const int wrel = w * 16;
  const int wo = __builtin_amdgcn_readfirstlane(O0 + wrel);  // abs out-ch base (SGPR)
  const int ri0 = (w >> 1) * 32;     // group input base, rel to block's 64 ch

  __shared__ float xs[IN_CH * XP];   // 21.1 KB
  __shared__ float h1s[64 * HP];     // 16.9 KB  (j <-> t = t0-2+j, j=0..63)
  __shared__ float h2s[64 * HP];     // 16.9 KB  (j <-> t = t0-1+j, j=0..61 valid)

  for (int e = tid; e < IN_CH * XP; e += 256) {
    int tt = e / IN_CH, c = e - tt * IN_CH;
    int t = t0 - 3 + tt;
    xs[c * XP + tt] = (t >= 0 && t < T_LEN) ? x[(b * T_LEN + t) * IN_CH + c] : 0.f;
  }
  __syncthreads();

  // ---- layer 1: lane l -> t = t0-2+l; reads xs j = l..l+2 ----
  {
    float acc[16];
#pragma unroll
    for (int h = 0; h < 2; ++h) {
#pragma unroll
      for (int oc = 0; oc < 8; ++oc) acc[8 * h + oc] = b1[wo + 8 * h + oc];
      conv8<IN_CH, XP>(xs, Wt1 + wo + 8 * h, l, acc + 8 * h);
    }
    int t = t0 - 2 + l;
    bool v = (t >= 0 && t < T_LEN);
#pragma unroll
    for (int oc = 0; oc < 16; ++oc)
      h1s[(wrel + oc) * HP + l] = v ? fmaxf(acc[oc], 0.f) : 0.f;
  }
  __syncthreads();

  // ---- layer 2: lane l -> t = t0-1+l (valid l<=61); reads h1s j = l..l+2 ----
  {
    float acc[16];
#pragma unroll
    for (int h = 0; h < 2; ++h) {
#pragma unroll
      for (int oc = 0; oc < 8; ++oc) acc[8 * h + oc] = b2[wo + 8 * h + oc];
      conv8<32, HP>(h1s + ri0 * HP, Wt2 + wo + 8 * h, l, acc + 8 * h);
    }
    int t = t0 - 1 + l;
    bool v = (t >= 0 && t < T_LEN);
#pragma unroll
    for (int oc = 0; oc < 16; ++oc)
      h2s[(wrel + oc) * HP + l] = v ? fmaxf(acc[oc], 0.f) : 0.f;
  }
  __syncthreads();

  // ---- layer 3: lane l -> t = t0+l (store l<60); reads h2s j = l..l+2 ----
  {
    float acc[16];
#pragma unroll
    for (int h = 0; h < 2; ++h) {
#pragma unroll
      for (int oc = 0; oc < 8; ++oc) acc[8 * h + oc] = b3[wo + 8 * h + oc];
      conv8<32, HP>(h2s + ri0 * HP, Wt3 + wo + 8 * h, l, acc + 8 * h);
    }
    int t = t0 + l;
    if (l < TTILE && t < T_LEN) {
      uint pk[8];
#pragma unroll
      for (int q = 0; q < 8; ++q) {
        __hip_bfloat16 lo = __float2bfloat16(fmaxf(acc[2 * q], 0.f));
        __hip_bfloat16 hi = __float2bfloat16(fmaxf(acc[2 * q + 1], 0.f));
        pk[q] = (uint)(*(ushort*)&lo) | ((uint)(*(ushort*)&hi) << 16);
      }
      uint4* dst = (uint4*)(out + (size_t)(b * T_LEN + t) * CONV_CH + wo);
      dst[0] = make_uint4(pk[0], pk[1], pk[2], pk[3]);
      dst[1] = make_uint4(pk[4], pk[5], pk[6], pk[7]);
    }
  }
}

// ============ conv4 as MFMA GEMM, K-split x4: 512 blocks (2/CU) ===============
#define APITCH 264
#define BPITCH 40
#define PSTRIDE 1792000
__global__ __launch_bounds__(256) void k_conv4m(
    const __hip_bfloat16* __restrict__ h3, const __hip_bfloat16* __restrict__ Wc,
    const float* __restrict__ bias, float* __restrict__ Pbase) {
  const int mb = blockIdx.x, b = blockIdx.y, ks = blockIdx.z;
  float* __restrict__ P = Pbase + (size_t)ks * PSTRIDE;
  const int t0 = mb * 64;
  const int tid = threadIdx.x;
  const int w = tid >> 6, lane = tid & 63;
  const int wm = w >> 1, wn = w & 1;
  const int lm = lane & 31, half = lane >> 5;

  __shared__ short h3s[67 * APITCH];
  __shared__ short Bs[2][256 * BPITCH];

  const ushort* h3u = (const ushort*)h3;
  for (int g = tid; g < 67 * 64; g += 256) {
    int rr = g >> 6, c4 = g & 63;
    int t = t0 + rr - 1;
    uint2 v = make_uint2(0u, 0u);
    if (t >= 0 && t < T_LEN)
      v = *(const uint2*)(h3u + (b * T_LEN + t) * CONV_CH + c4 * 4);
    *(uint2*)(h3s + rr * APITCH + c4 * 4) = v;
  }

  const ushort* Wu = (const ushort*)(Wc) + (size_t)(ks * 6) * 8192;
#pragma unroll
  for (int it = 0; it < 4; ++it) {
    int idx = (it * 256 + tid) * 8;
    uint4 v = *(const uint4*)(Wu + idx);
    int n = idx >> 5, kloc = idx & 31;
    *(uint4*)(Bs[0] + n * BPITCH + kloc) = v;
  }
  __syncthreads();

  f16v acc0 = {}, acc1 = {}, acc2 = {}, acc3 = {};

  for (int ch = 0; ch < 6; ++ch) {
    const int p = ch & 1;
    if (ch < 5) {
      const ushort* src = Wu + (ch + 1) * 8192;
#pragma unroll
      for (int it = 0; it < 4; ++it) {
        int idx = (it * 256 + tid) * 8;
        uint4 v = *(const uint4*)(src + idx);
        int n = idx >> 5, kloc = idx & 31;
        *(uint4*)(Bs[p ^ 1] + n * BPITCH + kloc) = v;
      }
    }
#pragma unroll
    for (int s = 0; s < 2; ++s) {
      int k0 = ks * 192 + ch * 32 + s * 16;
      int kappa = k0 >> 8, i0 = k0 & 255;
      s8v a = *(const s8v*)(h3s + (wm * 32 + lm + kappa) * APITCH + i0 + half * 8);
      const short* bp = Bs[p] + (wn * 128 + lm) * BPITCH + s * 16 + half * 8;
      s8v b0 = *(const s8v*)(bp);
      s8v b1 = *(const s8v*)(bp + 32 * BPITCH);
      s8v b2 = *(const s8v*)(bp + 64 * BPITCH);
      s8v b3 = *(const s8v*)(bp + 96 * BPITCH);
      acc0 = __builtin_amdgcn_mfma_f32_32x32x16_bf16(a, b0, acc0, 0, 0, 0);
      acc1 = __builtin_amdgcn_mfma_f32_32x32x16_bf16(a, b1, acc1, 0, 0, 0);
      acc2 = __builtin_amdgcn_mfma_f32_32x32x16_bf16(a, b2, acc2, 0, 0, 0);
      acc3 = __builtin_amdgcn_mfma_f32_32x32x16_bf16(a, b3, acc3, 0, 0, 0);
    }
    __syncthreads();
  }

  const int col = lm;
#pragma unroll
  for (int nt = 0; nt < 4; ++nt) {
    int c = wn * 128 + nt * 32 + col;
    if (c >= CCEP_N) continue;
    float bq = 0.f;
    if (ks == 0) {
      float invq = 1.f / (float)((c < 111) ? (111 - c) : (c - 110));
      bq = bias[c] * invq;
    }
    const f16v* A = (nt == 0) ? &acc0 : (nt == 1) ? &acc1 : (nt == 2) ? &acc2 : &acc3;
#pragma unroll
    for (int reg = 0; reg < 16; ++reg) {
      int row = (reg & 3) + 8 * (reg >> 2) + 4 * half;
      int t = t0 + wm * 32 + row;
      if (t < T_LEN)
        P[(size_t)(b * T_LEN + t) * 224 + c] = (*A)[reg] + bq;
    }
  }
}

// ============================ fused FFT kernel (2 frames/block) ===============
// Frames tA=2u, tB=2u+1. Two packed forward FFTs (c + i*fr per frame); S_A, S_B
// Hermitian -> ONE inverse: Z = S_A + i*S_B, IFFT(Z) = C_A + i*C_B (both real).
// Odd rows stored directly; even-row contributions spilled to sbl/sbr; no atomics.
__device__ __forceinline__ float2 cmul(float2 a, float2 b) {
  return make_float2(fmaf(a.x, b.x, -(a.y * b.y)), fmaf(a.x, b.y, a.y * b.x));
}
__device__ __forceinline__ float2 cadd(float2 a, float2 b) { return make_float2(a.x + b.x, a.y + b.y); }
__device__ __forceinline__ float2 csub(float2 a, float2 b) { return make_float2(a.x - b.x, a.y - b.y); }

#define LIDX(i) ((i) + ((i) >> 2))

template <int Q, int OFF>
__device__ __forceinline__ void fwd_stage2(float2* __restrict__ A,
    float2* __restrict__ B, const float2* __restrict__ Tw, int j) {
  const int pos = j & (Q - 1);
  const int base = ((j - pos) << 2) + pos;
  float2 e1 = Tw[OFF + pos], e2 = Tw[OFF + Q + pos], e3 = Tw[OFF + 2 * Q + pos];
  const float2 w1 = make_float2(e1.x, -e1.y);
  const float2 w2 = make_float2(e2.x, -e2.y);
  const float2 w3 = make_float2(e3.x, -e3.y);
#pragma unroll
  for (int arr = 0; arr < 2; ++arr) {
    float2* X = arr ? B : A;
    float2 a = X[LIDX(base)], b = X[LIDX(base + Q)];
    float2 cc = X[LIDX(base + 2 * Q)], d = X[LIDX(base + 3 * Q)];
    float2 t0 = cadd(a, cc), t1 = csub(a, cc), t2 = cadd(b, d), bd = csub(b, d);
    float2 t3 = make_float2(bd.y, -bd.x);
    X[LIDX(base)]         = cadd(t0, t2);
    X[LIDX(base + Q)]     = cmul(cadd(t1, t3), w1);
    X[LIDX(base + 2 * Q)] = cmul(csub(t0, t2), w2);
    X[LIDX(base + 3 * Q)] = cmul(csub(t1, t3), w3);
  }
}

template <int Q, int OFF>
__device__ __forceinline__ void inv_stage_t(float2* __restrict__ X,
    const float2* __restrict__ Tw, int j) {
  const int pos = j & (Q - 1);
  const int base = ((j - pos) << 2) + pos;
  const float2 w1 = Tw[OFF + pos];
  const float2 w2 = Tw[OFF + Q + pos];
  const float2 w3 = Tw[OFF + 2 * Q + pos];
  float2 a = X[LIDX(base)];
  float2 b = cmul(X[LIDX(base + Q)], w1);
  float2 cc = cmul(X[LIDX(base + 2 * Q)], w2);
  float2 d = cmul(X[LIDX(base + 3 * Q)], w3);
  float2 t0 = cadd(a, cc), t1 = csub(a, cc), t2 = cadd(b, d), bd = csub(b, d);
  float2 t3 = make_float2(-bd.y, bd.x);
  X[LIDX(base)]         = cadd(t0, t2);
  X[LIDX(base + Q)]     = cadd(t1, t3);
  X[LIDX(base + 2 * Q)] = csub(t0, t2);
  X[LIDX(base + 3 * Q)] = csub(t1, t3);
}

__device__ __forceinline__ int rev4d(int v) {
  return ((v & 3) << 6) | (((v >> 2) & 3) << 4) | (((v >> 4) & 3) << 2) | ((v >> 6) & 3);
}

// grid (500, 8)
__global__ __launch_bounds__(256) void k_fft(const float* __restrict__ Pb,
    const float* __restrict__ z, const float2* __restrict__ twg,
    const float* __restrict__ wing, float* __restrict__ out,
    float* __restrict__ sbl, float* __restrict__ sbr) {
  const int u = blockIdx.x, b = blockIdx.y;
  const int tA = 2 * u, tB = tA + 1;
  const int btA = b * T_LEN + tA, btB = btA + 1;
  const int j = threadIdx.x;
  __shared__ float2 WlA[1280];
  __shared__ float2 WlB[1280];
  __shared__ float2 Tws[1020];
  for (int e = j; e < 1020; e += 256) Tws[e] = twg[e];

  const float* zb = z + b * 256000;
  float f0A = 0.f, fS, f1B = 0.f;
  {
    int zi0 = tA * 256 + j - 255;
    f0A = (zi0 >= 0) ? zb[zi0] : 0.f;
    fS = zb[tA * 256 + j + 1];
    int zi2 = tB * 256 + j + 1;
    f1B = (zi2 < 256000) ? zb[zi2] : 0.f;
  }
  float c1A = 0.f, c2A = 0.f, c1B = 0.f, c2B = 0.f;
  if (j >= 145) {
    int mA = btA * 224 + (j - 145), mB = btB * 224 + (j - 145);
    c1A = (Pb[mA] + Pb[mA + PSTRIDE]) + (Pb[mA + 2 * PSTRIDE] + Pb[mA + 3 * PSTRIDE]);
    c1B = (Pb[mB] + Pb[mB + PSTRIDE]) + (Pb[mB + 2 * PSTRIDE] + Pb[mB + 3 * PSTRIDE]);
  }
  if (j < 111) {
    int mA = btA * 224 + (j + 111), mB = btB * 224 + (j + 111);
    c2A = (Pb[mA] + Pb[mA + PSTRIDE]) + (Pb[mA + 2 * PSTRIDE] + Pb[mA + 3 * PSTRIDE]);
    c2B = (Pb[mB] + Pb[mB + PSTRIDE]) + (Pb[mB + 2 * PSTRIDE] + Pb[mB + 3 * PSTRIDE]);
  }
  __syncthreads();

  {
    float2 e1 = Tws[j], e2 = Tws[256 + j], e3 = Tws[512 + j];
    const float2 w1 = make_float2(e1.x, -e1.y);
    const float2 w2 = make_float2(e2.x, -e2.y);
    const float2 w3 = make_float2(e3.x, -e3.y);
    {
      float2 t0 = make_float2(c2A, f0A);
      float2 t1 = make_float2(-c2A, f0A);
      float2 t2 = make_float2(c1A, fS);
      float2 t3 = make_float2(fS, -c1A);
      WlA[LIDX(j)]       = cadd(t0, t2);
      WlA[LIDX(j + 256)] = cmul(cadd(t1, t3), w1);
      WlA[LIDX(j + 512)] = cmul(csub(t0, t2), w2);
      WlA[LIDX(j + 768)] = cmul(csub(t1, t3), w3);
    }
    {
      float2 t0 = make_float2(c2B, fS);
      float2 t1 = make_float2(-c2B, fS);
      float2 t2 = make_float2(c1B, f1B);
      float2 t3 = make_float2(f1B, -c1B);
      WlB[LIDX(j)]       = cadd(t0, t2);
      WlB[LIDX(j + 256)] = cmul(cadd(t1, t3), w1);
      WlB[LIDX(j + 512)] = cmul(csub(t0, t2), w2);
      WlB[LIDX(j + 768)] = cmul(csub(t1, t3), w3);
    }
  }
  __syncthreads();

  fwd_stage2<64, 768>(WlA, WlB, Tws, j);  __syncthreads();
  fwd_stage2<16, 960>(WlA, WlB, Tws, j);  __syncthreads();
  fwd_stage2<4, 1008>(WlA, WlB, Tws, j);  __syncthreads();

  const int base = 4 * j;
  float2 XA[4], XB[4];
  {
    float2 u0 = WlA[LIDX(base)], u1 = WlA[LIDX(base + 1)];
    float2 u2 = WlA[LIDX(base + 2)], u3 = WlA[LIDX(base + 3)];
    float2 t0 = cadd(u0, u2), t1 = csub(u0, u2), t2 = cadd(u1, u3), bd = csub(u1, u3);
    float2 t3 = make_float2(bd.y, -bd.x);
    XA[0] = cadd(t0, t2); XA[1] = cadd(t1, t3); XA[2] = csub(t0, t2); XA[3] = csub(t1, t3);
  }
  {
    float2 u0 = WlB[LIDX(base)], u1 = WlB[LIDX(base + 1)];
    float2 u2 = WlB[LIDX(base + 2)], u3 = WlB[LIDX(base + 3)];
    float2 t0 = cadd(u0, u2), t1 = csub(u0, u2), t2 = cadd(u1, u3), bd = csub(u1, u3);
    float2 t3 = make_float2(bd.y, -bd.x);
    XB[0] = cadd(t0, t2); XB[1] = cadd(t1, t3); XB[2] = csub(t0, t2); XB[3] = csub(t1, t3);
  }
#pragma unroll
  for (int q = 0; q < 4; ++q) { WlA[LIDX(base + q)] = XA[q]; WlB[LIDX(base + q)] = XB[q]; }
  __syncthreads();

  const int r0 = rev4d(j);
  const bool self0 = (r0 == 0);
  const int jp = self0 ? 0 : rev4d((256 - r0) & 255);
  float2 PA[4], PB[4];
#pragma unroll
  for (int q = 0; q < 4; ++q) { PA[q] = WlA[LIDX(4 * jp + q)]; PB[q] = WlB[LIDX(4 * jp + q)]; }
  float2 Z[4];
#pragma unroll
  for (int q = 0; q < 4; ++q) {
    float2 SA, SB;
    {
      float2 A = XA[q];
      float2 Bc = self0 ? PA[(4 - q) & 3] : PA[3 - q];
      float2 Y = make_float2(0.5f * (A.x + Bc.x), 0.5f * (A.y - Bc.y));
      float2 F = make_float2(0.5f * (A.y + Bc.y), -0.5f * (A.x - Bc.x));
      float mag = __expf(Y.x * 2.30258509299404568402f);
      float sy, cy;
      __sincosf(Y.y, &sy, &cy);
      float gr = mag * cy, gi = mag * sy;
      SA = make_float2(fmaf(F.x, gr, F.y * gi), fmaf(F.x, gi, -(F.y * gr)));
    }
    {
      float2 A = XB[q];
      float2 Bc = self0 ? PB[(4 - q) & 3] : PB[3 - q];
      float2 Y = make_float2(0.5f * (A.x + Bc.x), 0.5f * (A.y - Bc.y));
      float2 F = make_float2(0.5f * (A.y + Bc.y), -0.5f * (A.x - Bc.x));
      float mag = __expf(Y.x * 2.30258509299404568402f);
      float sy, cy;
      __sincosf(Y.y, &sy, &cy);
      float gr = mag * cy, gi = mag * sy;
      SB = make_float2(fmaf(F.x, gr, F.y * gi), fmaf(F.x, gi, -(F.y * gr)));
    }
    Z[q] = make_float2(SA.x - SB.y, SA.y + SB.x);   // S_A + i*S_B
  }
  __syncthreads();

  {
    float2 t0 = cadd(Z[0], Z[2]), t1 = csub(Z[0], Z[2]), t2 = cadd(Z[1], Z[3]), bd = csub(Z[1], Z[3]);
    float2 t3 = make_float2(-bd.y, bd.x);
    WlA[LIDX(base)]     = cadd(t0, t2);
    WlA[LIDX(base + 1)] = cadd(t1, t3);
    WlA[LIDX(base + 2)] = csub(t0, t2);
    WlA[LIDX(base + 3)] = csub(t1, t3);
  }
  __syncthreads();

  inv_stage_t<4, 1008>(WlA, Tws, j);  __syncthreads();
  inv_stage_t<16, 960>(WlA, Tws, j);  __syncthreads();
  inv_stage_t<64, 768>(WlA, Tws, j);  __syncthreads();

  {
    float2 w1 = Tws[j], w2 = Tws[256 + j], w3 = Tws[512 + j];
    float2 a = WlA[LIDX(j)];
    float2 bb = cmul(WlA[LIDX(j + 256)], w1);
    float2 cc = cmul(WlA[LIDX(j + 512)], w2);
    float2 d = cmul(WlA[LIDX(j + 768)], w3);
    float2 t0 = cadd(a, cc), t1 = csub(a, cc), t2 = cadd(bb, d), bd = csub(bb, d);
    float2 t3 = make_float2(-bd.y, bd.x);
    float2 Cj    = cadd(t0, t2);   // C[j]     -> corr n1 = 511-j (r-part)
    float2 Cj256 = cadd(t1, t3);   // C[j+256] -> corr n2 = 255-j (l-part)
    int n1 = 511 - j, n2 = 255 - j;
    float wn1 = wing[n1], wn2 = wing[n2];
    float vA_l = Cj256.x * wn2;                 // even row tA contribution (l)
    float vAB  = Cj.x * wn1 + Cj256.y * wn2;    // odd row tB: A.r + B.l (owned)
    float vB_r = Cj.y * wn1;                    // even row tB+1 contribution (r)
    out[(b * T_LEN + tB) * 256 + n2] = vAB;
    int su = (b * 500 + u) * 256 + n2;
    sbl[su] = vA_l;
    sbr[su] = vB_r;
  }
}

// ---- even rows: out[b, 2u, n] = l(2u) + r(2u-1 mod 1000) ---------------------
__global__ __launch_bounds__(256) void k_even(const float* __restrict__ sbl,
    const float* __restrict__ sbr, float* __restrict__ out) {
  int idx = blockIdx.x * 256 + threadIdx.x;   // 1,024,000
  int n = idx & 255;
  int bu = idx >> 8;                          // b*500 + u
  int u = bu % 500, b = bu / 500;
  int up = (u == 0) ? 499 : u - 1;
  out[(b * T_LEN + 2 * u) * 256 + n] = sbl[idx] + sbr[(b * 500 + up) * 256 + n];
}

extern "C" void kernel_launch(void* const* d_in, const int* in_sizes, int n_in,
                              void* d_out, int out_size, void* d_ws, size_t ws_size,
                              hipStream_t stream) {
  const float* x  = (const float*)d_in[0];
  const float* z  = (const float*)d_in[1];
  const float* W1 = (const float*)d_in[2];
  const float* b1 = (const float*)d_in[3];
  const float* W2 = (const float*)d_in[4];
  const float* b2 = (const float*)d_in[5];
  const float* W3 = (const float*)d_in[6];
  const float* b3 = (const float*)d_in[7];
  const float* W4 = (const float*)d_in[8];
  const float* b4 = (const float*)d_in[9];

  float* ws   = (float*)d_ws;
  __hip_bfloat16* h3bf = (__hip_bfloat16*)ws;              // 1,024,000 f32 slots
  float* Pb   = ws + 1024000;            // 4 x 1,792,000 = 7,168,000
  float* sbl  = ws + 8192000;            // 1,024,000
  float* sbr  = ws + 9216000;            // 1,024,000
  float* Wt1  = ws + 10240000;           //    61,440
  float* Wt2  = ws + 10301440;           //    24,576
  float* Wt3  = ws + 10326016;           //    24,576
  __hip_bfloat16* Wc = (__hip_bfloat16*)(ws + 10350592);   // 98,304 f32 slots
  float2* twTab = (float2*)(ws + 10448896);                // 1020 float2
  float* winTab = ws + 10450944;                           // 512
  float* out = (float*)d_out;

  dim3 blk(256);
  k_prep<<<1206, blk, 0, stream>>>(W1, W2, W3, W4, Wt1, Wt2, Wt3, Wc,
                                   twTab, winTab);

  dim3 cgrid(17, B_N, 4);          // 17 t-tiles x 8 batches x 4 o-blocks
  k_convall<<<cgrid, blk, 0, stream>>>(x, Wt1, b1, Wt2, b2, Wt3, b3, h3bf);
  dim3 g4(16, B_N, 4);
  k_conv4m<<<g4, blk, 0, stream>>>(h3bf, Wc, b4, Pb);
  dim3 gf(T_LEN / 2, B_N);         // (500, 8)
  k_fft<<<gf, blk, 0, stream>>>(Pb, z, twTab, winTab, out, sbl, sbr);
  k_even<<<4000, blk, 0, stream>>>(sbl, sbr, out);
}

// Round 5
// 175.586 us; speedup vs baseline: 1.1842x; 1.1842x over previous
//
#include <hip/hip_runtime.h>
#include <hip/hip_bf16.h>

#define T_LEN 1000
#define B_N 8
#define IN_CH 80
#define CONV_CH 256
#define CCEP_N 222

typedef short s8v __attribute__((ext_vector_type(8)));    // 8 bf16 (4 VGPRs)
typedef float f16v __attribute__((ext_vector_type(16)));  // MFMA 32x32 acc

#define TWO_PI 6.28318530717958647692f

// ===================== fused prep kernel (weights + tables) ===================
// Conv1-3 weights stored interleaved: F4[(i4*3 + tap)*256 + o] holds the 4
// weights for input channels 4*i4..4*i4+3 (tap, out o). Lane o reads float4 at
// stride-16B across the wave -> 1KiB coalesced per instruction.
// blocks [0,240): W1; [240,336): W2; [336,432): W3; [432,1200): W4 chunks;
// [1200,1206): twiddle (1020 float2) + window (512).
__global__ __launch_bounds__(256) void k_prep(
    const float* __restrict__ W1, const float* __restrict__ W2,
    const float* __restrict__ W3, const float* __restrict__ W4,
    float* __restrict__ Wt1, float* __restrict__ Wt2, float* __restrict__ Wt3,
    __hip_bfloat16* __restrict__ Wc, float2* __restrict__ twTab,
    float* __restrict__ winTab) {
  const int bid = blockIdx.x, tid = threadIdx.x;
  if (bid < 240) {
    int e = bid * 256 + tid;                 // 61440 = 20*3*256*4
    int p = e & 3;
    int r = e >> 2;
    int o = r & 255;
    int s = r >> 8;                          // i4*3 + k, 0..59
    int k = s % 3, i4 = s / 3;
    Wt1[e] = W1[o * 240 + (4 * i4 + p) * 3 + k];   // W1 is (256, 80, 3)
  } else if (bid < 336) {
    int e = (bid - 240) * 256 + tid;         // 24576 = 8*3*256*4
    int p = e & 3;
    int r = e >> 2;
    int o = r & 255;
    int s = r >> 8;                          // i4*3 + k, 0..23
    int k = s % 3, i4 = s / 3;
    Wt2[e] = W2[o * 96 + (4 * i4 + p) * 3 + k];    // W2 is (256, 32, 3)
  } else if (bid < 432) {
    int e = (bid - 336) * 256 + tid;
    int p = e & 3;
    int r = e >> 2;
    int o = r & 255;
    int s = r >> 8;
    int k = s % 3, i4 = s / 3;
    Wt3[e] = W3[o * 96 + (4 * i4 + p) * 3 + k];
  } else if (bid < 1200) {
    int e = (bid - 432) * 256 + tid;         // 196608
    int kloc = e & 31, n = (e >> 5) & 255, chg = e >> 13;
    int kp = chg * 32 + kloc;
    int kappa = kp >> 8, i = kp & 255;
    float v = 0.f;
    if (n < CCEP_N) {
      float invq = 1.f / (float)((n < 111) ? (111 - n) : (n - 110));
      v = W4[n * 768 + i * 3 + kappa] * invq;
    }
    Wc[e] = __float2bfloat16(v);
  } else {
    int e = (bid - 1200) * 256 + tid;        // 0..1535
    if (e < 1020) {
      int Q, off;
      if (e < 768)       { Q = 256; off = 0; }
      else if (e < 960)  { Q = 64;  off = 768; }
      else if (e < 1008) { Q = 16;  off = 960; }
      else               { Q = 4;   off = 1008; }
      int rem = e - off;
      int r = rem / Q, pos = rem - r * Q;
      float ang = (TWO_PI * (float)((r + 1) * pos)) / (float)(4 * Q);
      float s, c;
      sincosf(ang, &s, &c);
      twTab[e] = make_float2(c, s);
    } else if (e < 1532) {
      int n = e - 1020;
      winTab[n] = (0.5f - 0.5f * cosf(TWO_PI * (float)n / 512.f)) * (1.f / 1024.f);
    }
  }
}

// ===== fully fused conv stack: x -> h1 (LDS) -> h2 (LDS) -> h3 bf16 ===========
// Round-0 structure (256 thr, o = out-channel, TT=10, pitch 18/14, float2
// activation reads) + ONE change: weights come from the interleaved float4
// layout and are REGISTER DOUBLE-BUFFERED — the next 4-channel chunk's 3
// dwordx4 issue at iteration top and are consumed one full chunk (168 FMAs,
// ~336 cy) later, covering the ~200 cy L2 latency that capped VALUBusy at 45%.
template <int NJ, int NI4, int PITCH, int NA2>
__device__ __forceinline__ void conv_acc(const float* __restrict__ abase,
    const float4* __restrict__ wq, float* __restrict__ acc) {
  float4 c0 = wq[0], c1 = wq[256], c2 = wq[512];
  for (int ig = 0; ig < NI4; ++ig) {
    const int nx = (ig + 1 < NI4) ? (ig + 1) : (NI4 - 1);
    float4 n0 = wq[(nx * 3 + 0) * 256];
    float4 n1 = wq[(nx * 3 + 1) * 256];
    float4 n2 = wq[(nx * 3 + 2) * 256];
#pragma unroll
    for (int s = 0; s < 4; ++s) {
      const float* row = abase + (4 * ig + s) * PITCH;
      float a[2 * NA2];
#pragma unroll
      for (int u = 0; u < NA2; ++u)
        *(float2*)&a[2 * u] = *(const float2*)(row + 2 * u);
      const float f0 = ((const float*)&c0)[s];
      const float f1 = ((const float*)&c1)[s];
      const float f2 = ((const float*)&c2)[s];
#pragma unroll
      for (int jl = 0; jl < NJ; ++jl) {
        acc[jl] = fmaf(a[jl], f0, acc[jl]);
        acc[jl] = fmaf(a[jl + 1], f1, acc[jl]);
        acc[jl] = fmaf(a[jl + 2], f2, acc[jl]);
      }
    }
    c0 = n0; c1 = n1; c2 = n2;
  }
}

__global__ __launch_bounds__(256) void k_convall(const float* __restrict__ x,
    const float* __restrict__ Wt1, const float* __restrict__ b1,
    const float* __restrict__ Wt2, const float* __restrict__ b2,
    const float* __restrict__ Wt3, const float* __restrict__ b3,
    __hip_bfloat16* __restrict__ out) {
  const int b = blockIdx.y;
  const int t0 = blockIdx.x * 10;
  const int o = threadIdx.x;
  const int cb = (o >> 5) << 5;
  __shared__ float xs[IN_CH * 18];      // 16 rows used; pitch 18 (2-way free)
  __shared__ float hs1[CONV_CH * 14];
  __shared__ float hs2[CONV_CH * 14];
  for (int e = threadIdx.x; e < 16 * IN_CH; e += 256) {
    int r = e / IN_CH, c = e - r * IN_CH;
    int t = t0 - 3 + r;
    xs[c * 18 + r] = (t >= 0 && t < T_LEN) ? x[(b * T_LEN + t) * IN_CH + c] : 0.f;
  }
  __syncthreads();
  // ---- layer 1: h1 rows j=0..13 (t = t0-2+j), x rows j..j+2 ----
  {
    float acc[14];
    const float bv = b1[o];
#pragma unroll
    for (int j = 0; j < 14; j++) acc[j] = bv;
    conv_acc<14, 20, 18, 8>(&xs[0], (const float4*)Wt1 + o, acc);
#pragma unroll
    for (int j = 0; j < 14; j++) {
      int t = t0 - 2 + j;
      hs1[o * 14 + j] = (t >= 0 && t < T_LEN) ? fmaxf(acc[j], 0.f) : 0.f;
    }
  }
  __syncthreads();
  // ---- layer 2: h2 rows j=0..11 (t = t0-1+j), h1 rows j..j+2 ----
  {
    float acc[12];
    const float bv = b2[o];
#pragma unroll
    for (int j = 0; j < 12; j++) acc[j] = bv;
    conv_acc<12, 8, 14, 7>(&hs1[cb * 14], (const float4*)Wt2 + o, acc);
#pragma unroll
    for (int j = 0; j < 12; j++) {
      int t = t0 - 1 + j;
      hs2[o * 14 + j] = (t >= 0 && t < T_LEN) ? fmaxf(acc[j], 0.f) : 0.f;
    }
  }
  __syncthreads();
  // ---- layer 3: h3 rows j=0..9 (t = t0+j), h2 rows j..j+2 ----
  {
    float acc[10];
    const float bv = b3[o];
#pragma unroll
    for (int j = 0; j < 10; j++) acc[j] = bv;
    conv_acc<10, 8, 14, 6>(&hs2[cb * 14], (const float4*)Wt3 + o, acc);
#pragma unroll
    for (int j = 0; j < 10; j++)
      out[(b * T_LEN + t0 + j) * CONV_CH + o] = __float2bfloat16(fmaxf(acc[j], 0.f));
  }
}

// ============ conv4 as MFMA GEMM, K-split x4: 512 blocks (2/CU) ===============
#define APITCH 264
#define BPITCH 40
#define PSTRIDE 1792000
__global__ __launch_bounds__(256) void k_conv4m(
    const __hip_bfloat16* __restrict__ h3, const __hip_bfloat16* __restrict__ Wc,
    const float* __restrict__ bias, float* __restrict__ Pbase) {
  const int mb = blockIdx.x, b = blockIdx.y, ks = blockIdx.z;
  float* __restrict__ P = Pbase + (size_t)ks * PSTRIDE;
  const int t0 = mb * 64;
  const int tid = threadIdx.x;
  const int w = tid >> 6, lane = tid & 63;
  const int wm = w >> 1, wn = w & 1;
  const int lm = lane & 31, half = lane >> 5;

  __shared__ short h3s[67 * APITCH];
  __shared__ short Bs[2][256 * BPITCH];

  const ushort* h3u = (const ushort*)h3;
  for (int g = tid; g < 67 * 64; g += 256) {
    int rr = g >> 6, c4 = g & 63;
    int t = t0 + rr - 1;
    uint2 v = make_uint2(0u, 0u);
    if (t >= 0 && t < T_LEN)
      v = *(const uint2*)(h3u + (b * T_LEN + t) * CONV_CH + c4 * 4);
    *(uint2*)(h3s + rr * APITCH + c4 * 4) = v;
  }

  const ushort* Wu = (const ushort*)(Wc) + (size_t)(ks * 6) * 8192;
#pragma unroll
  for (int it = 0; it < 4; ++it) {
    int idx = (it * 256 + tid) * 8;
    uint4 v = *(const uint4*)(Wu + idx);
    int n = idx >> 5, kloc = idx & 31;
    *(uint4*)(Bs[0] + n * BPITCH + kloc) = v;
  }
  __syncthreads();

  f16v acc0 = {}, acc1 = {}, acc2 = {}, acc3 = {};

  for (int ch = 0; ch < 6; ++ch) {
    const int p = ch & 1;
    if (ch < 5) {
      const ushort* src = Wu + (ch + 1) * 8192;
#pragma unroll
      for (int it = 0; it < 4; ++it) {
        int idx = (it * 256 + tid) * 8;
        uint4 v = *(const uint4*)(src + idx);
        int n = idx >> 5, kloc = idx & 31;
        *(uint4*)(Bs[p ^ 1] + n * BPITCH + kloc) = v;
      }
    }
#pragma unroll
    for (int s = 0; s < 2; ++s) {
      int k0 = ks * 192 + ch * 32 + s * 16;
      int kappa = k0 >> 8, i0 = k0 & 255;
      s8v a = *(const s8v*)(h3s + (wm * 32 + lm + kappa) * APITCH + i0 + half * 8);
      const short* bp = Bs[p] + (wn * 128 + lm) * BPITCH + s * 16 + half * 8;
      s8v b0 = *(const s8v*)(bp);
      s8v b1 = *(const s8v*)(bp + 32 * BPITCH);
      s8v b2 = *(const s8v*)(bp + 64 * BPITCH);
      s8v b3 = *(const s8v*)(bp + 96 * BPITCH);
      acc0 = __builtin_amdgcn_mfma_f32_32x32x16_bf16(a, b0, acc0, 0, 0, 0);
      acc1 = __builtin_amdgcn_mfma_f32_32x32x16_bf16(a, b1, acc1, 0, 0, 0);
      acc2 = __builtin_amdgcn_mfma_f32_32x32x16_bf16(a, b2, acc2, 0, 0, 0);
      acc3 = __builtin_amdgcn_mfma_f32_32x32x16_bf16(a, b3, acc3, 0, 0, 0);
    }
    __syncthreads();
  }

  const int col = lm;
#pragma unroll
  for (int nt = 0; nt < 4; ++nt) {
    int c = wn * 128 + nt * 32 + col;
    if (c >= CCEP_N) continue;
    float bq = 0.f;
    if (ks == 0) {
      float invq = 1.f / (float)((c < 111) ? (111 - c) : (c - 110));
      bq = bias[c] * invq;
    }
    const f16v* A = (nt == 0) ? &acc0 : (nt == 1) ? &acc1 : (nt == 2) ? &acc2 : &acc3;
#pragma unroll
    for (int reg = 0; reg < 16; ++reg) {
      int row = (reg & 3) + 8 * (reg >> 2) + 4 * half;
      int t = t0 + wm * 32 + row;
      if (t < T_LEN)
        P[(size_t)(b * T_LEN + t) * 224 + c] = (*A)[reg] + bq;
    }
  }
}

// ============================ fused FFT kernel (2 frames/block) ===============
// Frames tA=2u, tB=2u+1. Two packed forward FFTs (c + i*fr per frame); S_A, S_B
// Hermitian -> ONE inverse: Z = S_A + i*S_B, IFFT(Z) = C_A + i*C_B (both real).
// Odd rows stored directly; even-row contributions spilled to sbl/sbr; no atomics.
__device__ __forceinline__ float2 cmul(float2 a, float2 b) {
  return make_float2(fmaf(a.x, b.x, -(a.y * b.y)), fmaf(a.x, b.y, a.y * b.x));
}
__device__ __forceinline__ float2 cadd(float2 a, float2 b) { return make_float2(a.x + b.x, a.y + b.y); }
__device__ __forceinline__ float2 csub(float2 a, float2 b) { return make_float2(a.x - b.x, a.y - b.y); }

#define LIDX(i) ((i) + ((i) >> 2))

template <int Q, int OFF>
__device__ __forceinline__ void fwd_stage2(float2* __restrict__ A,
    float2* __restrict__ B, const float2* __restrict__ Tw, int j) {
  const int pos = j & (Q - 1);
  const int base = ((j - pos) << 2) + pos;
  float2 e1 = Tw[OFF + pos], e2 = Tw[OFF + Q + pos], e3 = Tw[OFF + 2 * Q + pos];
  const float2 w1 = make_float2(e1.x, -e1.y);
  const float2 w2 = make_float2(e2.x, -e2.y);
  const float2 w3 = make_float2(e3.x, -e3.y);
#pragma unroll
  for (int arr = 0; arr < 2; ++arr) {
    float2* X = arr ? B : A;
    float2 a = X[LIDX(base)], b = X[LIDX(base + Q)];
    float2 cc = X[LIDX(base + 2 * Q)], d = X[LIDX(base + 3 * Q)];
    float2 t0 = cadd(a, cc), t1 = csub(a, cc), t2 = cadd(b, d), bd = csub(b, d);
    float2 t3 = make_float2(bd.y, -bd.x);
    X[LIDX(base)]         = cadd(t0, t2);
    X[LIDX(base + Q)]     = cmul(cadd(t1, t3), w1);
    X[LIDX(base + 2 * Q)] = cmul(csub(t0, t2), w2);
    X[LIDX(base + 3 * Q)] = cmul(csub(t1, t3), w3);
  }
}

template <int Q, int OFF>
__device__ __forceinline__ void inv_stage_t(float2* __restrict__ X,
    const float2* __restrict__ Tw, int j) {
  const int pos = j & (Q - 1);
  const int base = ((j - pos) << 2) + pos;
  const float2 w1 = Tw[OFF + pos];
  const float2 w2 = Tw[OFF + Q + pos];
  const float2 w3 = Tw[OFF + 2 * Q + pos];
  float2 a = X[LIDX(base)];
  float2 b = cmul(X[LIDX(base + Q)], w1);
  float2 cc = cmul(X[LIDX(base + 2 * Q)], w2);
  float2 d = cmul(X[LIDX(base + 3 * Q)], w3);
  float2 t0 = cadd(a, cc), t1 = csub(a, cc), t2 = cadd(b, d), bd = csub(b, d);
  float2 t3 = make_float2(-bd.y, bd.x);
  X[LIDX(base)]         = cadd(t0, t2);
  X[LIDX(base + Q)]     = cadd(t1, t3);
  X[LIDX(base + 2 * Q)] = csub(t0, t2);
  X[LIDX(base + 3 * Q)] = csub(t1, t3);
}

__device__ __forceinline__ int rev4d(int v) {
  return ((v & 3) << 6) | (((v >> 2) & 3) << 4) | (((v >> 4) & 3) << 2) | ((v >> 6) & 3);
}

// grid (500, 8)
__global__ __launch_bounds__(256) void k_fft(const float* __restrict__ Pb,
    const float* __restrict__ z, const float2* __restrict__ twg,
    const float* __restrict__ wing, float* __restrict__ out,
    float* __restrict__ sbl, float* __restrict__ sbr) {
  const int u = blockIdx.x, b = blockIdx.y;
  const int tA = 2 * u, tB = tA + 1;
  const int btA = b * T_LEN + tA, btB = btA + 1;
  const int j = threadIdx.x;
  __shared__ float2 WlA[1280];
  __shared__ float2 WlB[1280];
  __shared__ float2 Tws[1020];
  for (int e = j; e < 1020; e += 256) Tws[e] = twg[e];

  const float* zb = z + b * 256000;
  float f0A = 0.f, fS, f1B = 0.f;
  {
    int zi0 = tA * 256 + j - 255;
    f0A = (zi0 >= 0) ? zb[zi0] : 0.f;
    fS = zb[tA * 256 + j + 1];
    int zi2 = tB * 256 + j + 1;
    f1B = (zi2 < 256000) ? zb[zi2] : 0.f;
  }
  float c1A = 0.f, c2A = 0.f, c1B = 0.f, c2B = 0.f;
  if (j >= 145) {
    int mA = btA * 224 + (j - 145), mB = btB * 224 + (j - 145);
    c1A = (Pb[mA] + Pb[mA + PSTRIDE]) + (Pb[mA + 2 * PSTRIDE] + Pb[mA + 3 * PSTRIDE]);
    c1B = (Pb[mB] + Pb[mB + PSTRIDE]) + (Pb[mB + 2 * PSTRIDE] + Pb[mB + 3 * PSTRIDE]);
  }
  if (j < 111) {
    int mA = btA * 224 + (j + 111), mB = btB * 224 + (j + 111);
    c2A = (Pb[mA] + Pb[mA + PSTRIDE]) + (Pb[mA + 2 * PSTRIDE] + Pb[mA + 3 * PSTRIDE]);
    c2B = (Pb[mB] + Pb[mB + PSTRIDE]) + (Pb[mB + 2 * PSTRIDE] + Pb[mB + 3 * PSTRIDE]);
  }
  __syncthreads();

  {
    float2 e1 = Tws[j], e2 = Tws[256 + j], e3 = Tws[512 + j];
    const float2 w1 = make_float2(e1.x, -e1.y);
    const float2 w2 = make_float2(e2.x, -e2.y);
    const float2 w3 = make_float2(e3.x, -e3.y);
    {
      float2 t0 = make_float2(c2A, f0A);
      float2 t1 = make_float2(-c2A, f0A);
      float2 t2 = make_float2(c1A, fS);
      float2 t3 = make_float2(fS, -c1A);
      WlA[LIDX(j)]       = cadd(t0, t2);
      WlA[LIDX(j + 256)] = cmul(cadd(t1, t3), w1);
      WlA[LIDX(j + 512)] = cmul(csub(t0, t2), w2);
      WlA[LIDX(j + 768)] = cmul(csub(t1, t3), w3);
    }
    {
      float2 t0 = make_float2(c2B, fS);
      float2 t1 = make_float2(-c2B, fS);
      float2 t2 = make_float2(c1B, f1B);
      float2 t3 = make_float2(f1B, -c1B);
      WlB[LIDX(j)]       = cadd(t0, t2);
      WlB[LIDX(j + 256)] = cmul(cadd(t1, t3), w1);
      WlB[LIDX(j + 512)] = cmul(csub(t0, t2), w2);
      WlB[LIDX(j + 768)] = cmul(csub(t1, t3), w3);
    }
  }
  __syncthreads();

  fwd_stage2<64, 768>(WlA, WlB, Tws, j);  __syncthreads();
  fwd_stage2<16, 960>(WlA, WlB, Tws, j);  __syncthreads();
  fwd_stage2<4, 1008>(WlA, WlB, Tws, j);  __syncthreads();

  const int base = 4 * j;
  float2 XA[4], XB[4];
  {
    float2 u0 = WlA[LIDX(base)], u1 = WlA[LIDX(base + 1)];
    float2 u2 = WlA[LIDX(base + 2)], u3 = WlA[LIDX(base + 3)];
    float2 t0 = cadd(u0, u2), t1 = csub(u0, u2), t2 = cadd(u1, u3), bd = csub(u1, u3);
    float2 t3 = make_float2(bd.y, -bd.x);
    XA[0] = cadd(t0, t2); XA[1] = cadd(t1, t3); XA[2] = csub(t0, t2); XA[3] = csub(t1, t3);
  }
  {
    float2 u0 = WlB[LIDX(base)], u1 = WlB[LIDX(base + 1)];
    float2 u2 = WlB[LIDX(base + 2)], u3 = WlB[LIDX(base + 3)];
    float2 t0 = cadd(u0, u2), t1 = csub(u0, u2), t2 = cadd(u1, u3), bd = csub(u1, u3);
    float2 t3 = make_float2(bd.y, -bd.x);
    XB[0] = cadd(t0, t2); XB[1] = cadd(t1, t3); XB[2] = csub(t0, t2); XB[3] = csub(t1, t3);
  }
#pragma unroll
  for (int q = 0; q < 4; ++q) { WlA[LIDX(base + q)] = XA[q]; WlB[LIDX(base + q)] = XB[q]; }
  __syncthreads();

  const int r0 = rev4d(j);
  const bool self0 = (r0 == 0);
  const int jp = self0 ? 0 : rev4d((256 - r0) & 255);
  float2 PA[4], PB[4];
#pragma unroll
  for (int q = 0; q < 4; ++q) { PA[q] = WlA[LIDX(4 * jp + q)]; PB[q] = WlB[LIDX(4 * jp + q)]; }
  float2 Z[4];
#pragma unroll
  for (int q = 0; q < 4; ++q) {
    float2 SA, SB;
    {
      float2 A = XA[q];
      float2 Bc = self0 ? PA[(4 - q) & 3] : PA[3 - q];
      float2 Y = make_float2(0.5f * (A.x + Bc.x), 0.5f * (A.y - Bc.y));
      float2 F = make_float2(0.5f * (A.y + Bc.y), -0.5f * (A.x - Bc.x));
      float mag = __expf(Y.x * 2.30258509299404568402f);
      float sy, cy;
      __sincosf(Y.y, &sy, &cy);
      float gr = mag * cy, gi = mag * sy;
      SA = make_float2(fmaf(F.x, gr, F.y * gi), fmaf(F.x, gi, -(F.y * gr)));
    }
    {
      float2 A = XB[q];
      float2 Bc = self0 ? PB[(4 - q) & 3] : PB[3 - q];
      float2 Y = make_float2(0.5f * (A.x + Bc.x), 0.5f * (A.y - Bc.y));
      float2 F = make_float2(0.5f * (A.y + Bc.y), -0.5f * (A.x - Bc.x));
      float mag = __expf(Y.x * 2.30258509299404568402f);
      float sy, cy;
      __sincosf(Y.y, &sy, &cy);
      float gr = mag * cy, gi = mag * sy;
      SB = make_float2(fmaf(F.x, gr, F.y * gi), fmaf(F.x, gi, -(F.y * gr)));
    }
    Z[q] = make_float2(SA.x - SB.y, SA.y + SB.x);   // S_A + i*S_B
  }
  __syncthreads();

  {
    float2 t0 = cadd(Z[0], Z[2]), t1 = csub(Z[0], Z[2]), t2 = cadd(Z[1], Z[3]), bd = csub(Z[1], Z[3]);
    float2 t3 = make_float2(-bd.y, bd.x);
    WlA[LIDX(base)]     = cadd(t0, t2);
    WlA[LIDX(base + 1)] = cadd(t1, t3);
    WlA[LIDX(base + 2)] = csub(t0, t2);
    WlA[LIDX(base + 3)] = csub(t1, t3);
  }
  __syncthreads();

  inv_stage_t<4, 1008>(WlA, Tws, j);  __syncthreads();
  inv_stage_t<16, 960>(WlA, Tws, j);  __syncthreads();
  inv_stage_t<64, 768>(WlA, Tws, j);  __syncthreads();

  {
    float2 w1 = Tws[j], w2 = Tws[256 + j], w3 = Tws[512 + j];
    float2 a = WlA[LIDX(j)];
    float2 bb = cmul(WlA[LIDX(j + 256)], w1);
    float2 cc = cmul(WlA[LIDX(j + 512)], w2);
    float2 d = cmul(WlA[LIDX(j + 768)], w3);
    float2 t0 = cadd(a, cc), t1 = csub(a, cc), t2 = cadd(bb, d), bd = csub(bb, d);
    float2 t3 = make_float2(-bd.y, bd.x);
    float2 Cj    = cadd(t0, t2);   // C[j]     -> corr n1 = 511-j (r-part)
    float2 Cj256 = cadd(t1, t3);   // C[j+256] -> corr n2 = 255-j (l-part)
    int n1 = 511 - j, n2 = 255 - j;
    float wn1 = wing[n1], wn2 = wing[n2];
    float vA_l = Cj256.x * wn2;                 // even row tA contribution (l)
    float vAB  = Cj.x * wn1 + Cj256.y * wn2;    // odd row tB: A.r + B.l (owned)
    float vB_r = Cj.y * wn1;                    // even row tB+1 contribution (r)
    out[(b * T_LEN + tB) * 256 + n2] = vAB;
    int su = (b * 500 + u) * 256 + n2;
    sbl[su] = vA_l;
    sbr[su] = vB_r;
  }
}

// ---- even rows: out[b, 2u, n] = l(2u) + r(2u-1 mod 1000) ---------------------
__global__ __launch_bounds__(256) void k_even(const float* __restrict__ sbl,
    const float* __restrict__ sbr, float* __restrict__ out) {
  int idx = blockIdx.x * 256 + threadIdx.x;   // 1,024,000
  int n = idx & 255;
  int bu = idx >> 8;                          // b*500 + u
  int u = bu % 500, b = bu / 500;
  int up = (u == 0) ? 499 : u - 1;
  out[(b * T_LEN + 2 * u) * 256 + n] = sbl[idx] + sbr[(b * 500 + up) * 256 + n];
}

extern "C" void kernel_launch(void* const* d_in, const int* in_sizes, int n_in,
                              void* d_out, int out_size, void* d_ws, size_t ws_size,
                              hipStream_t stream) {
  const float* x  = (const float*)d_in[0];
  const float* z  = (const float*)d_in[1];
  const float* W1 = (const float*)d_in[2];
  const float* b1 = (const float*)d_in[3];
  const float* W2 = (const float*)d_in[4];
  const float* b2 = (const float*)d_in[5];
  const float* W3 = (const float*)d_in[6];
  const float* b3 = (const float*)d_in[7];
  const float* W4 = (const float*)d_in[8];
  const float* b4 = (const float*)d_in[9];

  float* ws   = (float*)d_ws;
  __hip_bfloat16* h3bf = (__hip_bfloat16*)ws;              // 1,024,000 f32 slots
  float* Pb   = ws + 1024000;            // 4 x 1,792,000 = 7,168,000
  float* sbl  = ws + 8192000;            // 1,024,000
  float* sbr  = ws + 9216000;            // 1,024,000
  float* Wt1  = ws + 10240000;           //    61,440
  float* Wt2  = ws + 10301440;           //    24,576
  float* Wt3  = ws + 10326016;           //    24,576
  __hip_bfloat16* Wc = (__hip_bfloat16*)(ws + 10350592);   // 98,304 f32 slots
  float2* twTab = (float2*)(ws + 10448896);                // 1020 float2
  float* winTab = ws + 10450944;                           // 512
  float* out = (float*)d_out;

  dim3 blk(256);
  k_prep<<<1206, blk, 0, stream>>>(W1, W2, W3, W4, Wt1, Wt2, Wt3, Wc,
                                   twTab, winTab);

  dim3 cgrid10(T_LEN / 10, B_N);   // (100, 8)
  k_convall<<<cgrid10, blk, 0, stream>>>(x, Wt1, b1, Wt2, b2, Wt3, b3, h3bf);
  dim3 g4(16, B_N, 4);
  k_conv4m<<<g4, blk, 0, stream>>>(h3bf, Wc, b4, Pb);
  dim3 gf(T_LEN / 2, B_N);         // (500, 8)
  k_fft<<<gf, blk, 0, stream>>>(Pb, z, twTab, winTab, out, sbl, sbr);
  k_even<<<4000, blk, 0, stream>>>(sbl, sbr, out);
}

// Round 6
// 157.997 us; speedup vs baseline: 1.3160x; 1.1113x over previous
//
#include <hip/hip_runtime.h>
#include <hip/hip_bf16.h>

#define T_LEN 1000
#define B_N 8
#define IN_CH 80
#define CONV_CH 256
#define CCEP_N 222

typedef short s8v __attribute__((ext_vector_type(8)));      // 8 bf16 (4 VGPRs)
typedef _Float16 h8v __attribute__((ext_vector_type(8)));   // 8 fp16 (4 VGPRs)
typedef float f16v __attribute__((ext_vector_type(16)));    // MFMA 32x32 acc

#define TWO_PI 6.28318530717958647692f

// ===================== fused prep kernel (weights + tables) ===================
// [0,3000): xf16 [8000][96] fp16 (ch 80..95 zero);
// [3000,3288): W1p [9][256][32] fp16, k = chg*32+kloc in [0,288), kappa=k/96, i=k%96;
// [3288,3384): W2p [3][256][32], k in [0,96), kappa=k>>5, iloc=k&31;
// [3384,3480): W3p same; [3480,4248): Wc (conv4 bf16, /quef fused);
// [4248,4254): twiddle (1020 float2) + window (512).
__global__ __launch_bounds__(256) void k_prep(
    const float* __restrict__ x,
    const float* __restrict__ W1, const float* __restrict__ W2,
    const float* __restrict__ W3, const float* __restrict__ W4,
    _Float16* __restrict__ xf, _Float16* __restrict__ W1p,
    _Float16* __restrict__ W2p, _Float16* __restrict__ W3p,
    __hip_bfloat16* __restrict__ Wc, float2* __restrict__ twTab,
    float* __restrict__ winTab) {
  const int bid = blockIdx.x, tid = threadIdx.x;
  if (bid < 3000) {
    int e = bid * 256 + tid;                 // 768000 = 8000*96
    int r = e / 96, c = e - r * 96;
    xf[e] = (c < IN_CH) ? (_Float16)x[r * IN_CH + c] : (_Float16)0.f;
  } else if (bid < 3288) {
    int e = (bid - 3000) * 256 + tid;        // 73728 = 9*8192
    int kloc = e & 31, n = (e >> 5) & 255, chg = e >> 13;
    int k = chg * 32 + kloc;
    int kappa = k / 96, i = k - kappa * 96;
    W1p[e] = (i < IN_CH) ? (_Float16)W1[n * 240 + i * 3 + kappa] : (_Float16)0.f;
  } else if (bid < 3384) {
    int e = (bid - 3288) * 256 + tid;        // 24576 = 3*8192
    int kloc = e & 31, n = (e >> 5) & 255, chg = e >> 13;
    int k = chg * 32 + kloc;
    int kappa = k >> 5, iloc = k & 31;
    W2p[e] = (_Float16)W2[n * 96 + iloc * 3 + kappa];
  } else if (bid < 3480) {
    int e = (bid - 3384) * 256 + tid;
    int kloc = e & 31, n = (e >> 5) & 255, chg = e >> 13;
    int k = chg * 32 + kloc;
    int kappa = k >> 5, iloc = k & 31;
    W3p[e] = (_Float16)W3[n * 96 + iloc * 3 + kappa];
  } else if (bid < 4248) {
    int e = (bid - 3480) * 256 + tid;        // 196608
    int kloc = e & 31, n = (e >> 5) & 255, chg = e >> 13;
    int kp = chg * 32 + kloc;
    int kappa = kp >> 8, i = kp & 255;
    float v = 0.f;
    if (n < CCEP_N) {
      float invq = 1.f / (float)((n < 111) ? (111 - n) : (n - 110));
      v = W4[n * 768 + i * 3 + kappa] * invq;
    }
    Wc[e] = __float2bfloat16(v);
  } else {
    int e = (bid - 4248) * 256 + tid;        // 0..1535
    if (e < 1020) {
      int Q, off;
      if (e < 768)       { Q = 256; off = 0; }
      else if (e < 960)  { Q = 64;  off = 768; }
      else if (e < 1008) { Q = 16;  off = 960; }
      else               { Q = 4;   off = 1008; }
      int rem = e - off;
      int r = rem / Q, pos = rem - r * Q;
      float ang = (TWO_PI * (float)((r + 1) * pos)) / (float)(4 * Q);
      float s, c;
      sincosf(ang, &s, &c);
      twTab[e] = make_float2(c, s);
    } else if (e < 1532) {
      int n = e - 1020;
      winTab[n] = (0.5f - 0.5f * cosf(TWO_PI * (float)n / 512.f)) * (1.f / 1024.f);
    }
  }
}

// ===== conv1-3 as MFMA fp16 GEMMs (clone of proven k_conv4m fragment scheme) ==
// Block: 256 thr = 4 waves; M-tile = 32 t's (t0=mb*32), N = 128 ch (z*128),
// wave w owns N-tile n0 = z*128+w*32. A staged rows t0-1..t0+32 (34, halo for
// the 3-tap shift kappa: A-row read = lm+kappa). B double-buffered per 32-k
// chunk, layout [n][kloc] pitch 40 (conv4m-proven). K: conv1 kk=kappa*96+i
// (288, x padded to 96 ch); conv2/3 grouped: N-tile==group, kk=kappa*32+iloc.
// fp32 accumulation; bias+relu epilogue; out fp16 (h1,h2) or bf16 (h3).
template <int NCHG, bool GROUPED, int ACH, int APH, bool OUTBF>
__global__ __launch_bounds__(256) void k_cgemm(
    const _Float16* __restrict__ A, const _Float16* __restrict__ Bp,
    const float* __restrict__ bias, void* __restrict__ outp) {
  const int mb = blockIdx.x, b = blockIdx.y, z = blockIdx.z;
  const int t0 = mb * 32;
  const int tid = threadIdx.x;
  const int w = tid >> 6, lane = tid & 63;
  const int lm = lane & 31, half = lane >> 5;

  __shared__ _Float16 As[34 * APH];
  __shared__ _Float16 Bs[2][128 * 40];

  constexpr int ACOLS = GROUPED ? 128 : ACH;   // staged cols
  constexpr int NCH4 = ACOLS / 4;              // uint2 (4 halves) per row
  for (int e = tid; e < 34 * NCH4; e += 256) {
    int rr = e / NCH4, c4 = e - rr * NCH4;
    int t = t0 - 1 + rr;
    uint2 v = make_uint2(0u, 0u);
    if (t >= 0 && t < T_LEN)
      v = *((const uint2*)(A + (size_t)(b * T_LEN + t) * ACH +
                           (GROUPED ? z * 128 : 0)) + c4);
    *(uint2*)(As + rr * APH + c4 * 4) = v;
  }
  {
    const _Float16* src = Bp + z * 4096;       // chunk 0, this block's 128 n
    for (int e = tid; e < 512; e += 256) {
      int nl = e >> 2, c4 = e & 3;
      *(uint4*)(Bs[0] + nl * 40 + c4 * 8) = *(const uint4*)(src + nl * 32 + c4 * 8);
    }
  }
  __syncthreads();

  f16v acc = {};
#pragma unroll
  for (int chg = 0; chg < NCHG; ++chg) {
    const int p = chg & 1;
    if (chg + 1 < NCHG) {
      const _Float16* src = Bp + (size_t)(chg + 1) * 8192 + z * 4096;
      for (int e = tid; e < 512; e += 256) {
        int nl = e >> 2, c4 = e & 3;
        *(uint4*)(Bs[p ^ 1] + nl * 40 + c4 * 8) = *(const uint4*)(src + nl * 32 + c4 * 8);
      }
    }
#pragma unroll
    for (int s = 0; s < 2; ++s) {
      const int c16 = chg * 2 + s;             // 16-k chunk index
      int kappa, icol;
      if constexpr (GROUPED) { kappa = c16 >> 1; icol = w * 32 + (c16 & 1) * 16; }
      else                   { kappa = c16 / 6; icol = (c16 - (c16 / 6) * 6) * 16; }
      h8v a  = *(const h8v*)(As + (lm + kappa) * APH + icol + half * 8);
      h8v bf = *(const h8v*)(Bs[p] + (w * 32 + lm) * 40 + s * 16 + half * 8);
      acc = __builtin_amdgcn_mfma_f32_32x32x16_f16(a, bf, acc, 0, 0, 0);
    }
    __syncthreads();
  }

  const int c = z * 128 + w * 32 + lm;
  const float bv = bias[c];
#pragma unroll
  for (int reg = 0; reg < 16; ++reg) {
    int row = (reg & 3) + 8 * (reg >> 2) + 4 * half;
    int t = t0 + row;
    if (t < T_LEN) {
      float v = fmaxf(acc[reg] + bv, 0.f);
      size_t idx = (size_t)(b * T_LEN + t) * CONV_CH + c;
      if constexpr (OUTBF) ((__hip_bfloat16*)outp)[idx] = __float2bfloat16(v);
      else                 ((_Float16*)outp)[idx] = (_Float16)v;
    }
  }
}

// ============ conv4 as MFMA GEMM, K-split x4: 512 blocks (2/CU) ===============
#define APITCH 264
#define BPITCH 40
#define PSTRIDE 1792000
__global__ __launch_bounds__(256) void k_conv4m(
    const __hip_bfloat16* __restrict__ h3, const __hip_bfloat16* __restrict__ Wc,
    const float* __restrict__ bias, float* __restrict__ Pbase) {
  const int mb = blockIdx.x, b = blockIdx.y, ks = blockIdx.z;
  float* __restrict__ P = Pbase + (size_t)ks * PSTRIDE;
  const int t0 = mb * 64;
  const int tid = threadIdx.x;
  const int w = tid >> 6, lane = tid & 63;
  const int wm = w >> 1, wn = w & 1;
  const int lm = lane & 31, half = lane >> 5;

  __shared__ short h3s[67 * APITCH];
  __shared__ short Bs[2][256 * BPITCH];

  const ushort* h3u = (const ushort*)h3;
  for (int g = tid; g < 67 * 64; g += 256) {
    int rr = g >> 6, c4 = g & 63;
    int t = t0 + rr - 1;
    uint2 v = make_uint2(0u, 0u);
    if (t >= 0 && t < T_LEN)
      v = *(const uint2*)(h3u + (b * T_LEN + t) * CONV_CH + c4 * 4);
    *(uint2*)(h3s + rr * APITCH + c4 * 4) = v;
  }

  const ushort* Wu = (const ushort*)(Wc) + (size_t)(ks * 6) * 8192;
#pragma unroll
  for (int it = 0; it < 4; ++it) {
    int idx = (it * 256 + tid) * 8;
    uint4 v = *(const uint4*)(Wu + idx);
    int n = idx >> 5, kloc = idx & 31;
    *(uint4*)(Bs[0] + n * BPITCH + kloc) = v;
  }
  __syncthreads();

  f16v acc0 = {}, acc1 = {}, acc2 = {}, acc3 = {};

  for (int ch = 0; ch < 6; ++ch) {
    const int p = ch & 1;
    if (ch < 5) {
      const ushort* src = Wu + (ch + 1) * 8192;
#pragma unroll
      for (int it = 0; it < 4; ++it) {
        int idx = (it * 256 + tid) * 8;
        uint4 v = *(const uint4*)(src + idx);
        int n = idx >> 5, kloc = idx & 31;
        *(uint4*)(Bs[p ^ 1] + n * BPITCH + kloc) = v;
      }
    }
#pragma unroll
    for (int s = 0; s < 2; ++s) {
      int k0 = ks * 192 + ch * 32 + s * 16;
      int kappa = k0 >> 8, i0 = k0 & 255;
      s8v a = *(const s8v*)(h3s + (wm * 32 + lm + kappa) * APITCH + i0 + half * 8);
      const short* bp = Bs[p] + (wn * 128 + lm) * BPITCH + s * 16 + half * 8;
      s8v b0 = *(const s8v*)(bp);
      s8v b1 = *(const s8v*)(bp + 32 * BPITCH);
      s8v b2 = *(const s8v*)(bp + 64 * BPITCH);
      s8v b3 = *(const s8v*)(bp + 96 * BPITCH);
      acc0 = __builtin_amdgcn_mfma_f32_32x32x16_bf16(a, b0, acc0, 0, 0, 0);
      acc1 = __builtin_amdgcn_mfma_f32_32x32x16_bf16(a, b1, acc1, 0, 0, 0);
      acc2 = __builtin_amdgcn_mfma_f32_32x32x16_bf16(a, b2, acc2, 0, 0, 0);
      acc3 = __builtin_amdgcn_mfma_f32_32x32x16_bf16(a, b3, acc3, 0, 0, 0);
    }
    __syncthreads();
  }

  const int col = lm;
#pragma unroll
  for (int nt = 0; nt < 4; ++nt) {
    int c = wn * 128 + nt * 32 + col;
    if (c >= CCEP_N) continue;
    float bq = 0.f;
    if (ks == 0) {
      float invq = 1.f / (float)((c < 111) ? (111 - c) : (c - 110));
      bq = bias[c] * invq;
    }
    const f16v* A = (nt == 0) ? &acc0 : (nt == 1) ? &acc1 : (nt == 2) ? &acc2 : &acc3;
#pragma unroll
    for (int reg = 0; reg < 16; ++reg) {
      int row = (reg & 3) + 8 * (reg >> 2) + 4 * half;
      int t = t0 + wm * 32 + row;
      if (t < T_LEN)
        P[(size_t)(b * T_LEN + t) * 224 + c] = (*A)[reg] + bq;
    }
  }
}

// ============================ fused FFT kernel (2 frames/block) ===============
// Frames tA=2u, tB=2u+1. Two packed forward FFTs (c + i*fr per frame); S_A, S_B
// Hermitian -> ONE inverse: Z = S_A + i*S_B, IFFT(Z) = C_A + i*C_B (both real).
// Odd rows stored directly; even-row contributions spilled to sbl/sbr; no atomics.
__device__ __forceinline__ float2 cmul(float2 a, float2 b) {
  return make_float2(fmaf(a.x, b.x, -(a.y * b.y)), fmaf(a.x, b.y, a.y * b.x));
}
__device__ __forceinline__ float2 cadd(float2 a, float2 b) { return make_float2(a.x + b.x, a.y + b.y); }
__device__ __forceinline__ float2 csub(float2 a, float2 b) { return make_float2(a.x - b.x, a.y - b.y); }

#define LIDX(i) ((i) + ((i) >> 2))

template <int Q, int OFF>
__device__ __forceinline__ void fwd_stage2(float2* __restrict__ A,
    float2* __restrict__ B, const float2* __restrict__ Tw, int j) {
  const int pos = j & (Q - 1);
  const int base = ((j - pos) << 2) + pos;
  float2 e1 = Tw[OFF + pos], e2 = Tw[OFF + Q + pos], e3 = Tw[OFF + 2 * Q + pos];
  const float2 w1 = make_float2(e1.x, -e1.y);
  const float2 w2 = make_float2(e2.x, -e2.y);
  const float2 w3 = make_float2(e3.x, -e3.y);
#pragma unroll
  for (int arr = 0; arr < 2; ++arr) {
    float2* X = arr ? B : A;
    float2 a = X[LIDX(base)], b = X[LIDX(base + Q)];
    float2 cc = X[LIDX(base + 2 * Q)], d = X[LIDX(base + 3 * Q)];
    float2 t0 = cadd(a, cc), t1 = csub(a, cc), t2 = cadd(b, d), bd = csub(b, d);
    float2 t3 = make_float2(bd.y, -bd.x);
    X[LIDX(base)]         = cadd(t0, t2);
    X[LIDX(base + Q)]     = cmul(cadd(t1, t3), w1);
    X[LIDX(base + 2 * Q)] = cmul(csub(t0, t2), w2);
    X[LIDX(base + 3 * Q)] = cmul(csub(t1, t3), w3);
  }
}

template <int Q, int OFF>
__device__ __forceinline__ void inv_stage_t(float2* __restrict__ X,
    const float2* __restrict__ Tw, int j) {
  const int pos = j & (Q - 1);
  const int base = ((j - pos) << 2) + pos;
  const float2 w1 = Tw[OFF + pos];
  const float2 w2 = Tw[OFF + Q + pos];
  const float2 w3 = Tw[OFF + 2 * Q + pos];
  float2 a = X[LIDX(base)];
  float2 b = cmul(X[LIDX(base + Q)], w1);
  float2 cc = cmul(X[LIDX(base + 2 * Q)], w2);
  float2 d = cmul(X[LIDX(base + 3 * Q)], w3);
  float2 t0 = cadd(a, cc), t1 = csub(a, cc), t2 = cadd(b, d), bd = csub(b, d);
  float2 t3 = make_float2(-bd.y, bd.x);
  X[LIDX(base)]         = cadd(t0, t2);
  X[LIDX(base + Q)]     = cadd(t1, t3);
  X[LIDX(base + 2 * Q)] = csub(t0, t2);
  X[LIDX(base + 3 * Q)] = csub(t1, t3);
}

__device__ __forceinline__ int rev4d(int v) {
  return ((v & 3) << 6) | (((v >> 2) & 3) << 4) | (((v >> 4) & 3) << 2) | ((v >> 6) & 3);
}

// grid (500, 8)
__global__ __launch_bounds__(256) void k_fft(const float* __restrict__ Pb,
    const float* __restrict__ z, const float2* __restrict__ twg,
    const float* __restrict__ wing, float* __restrict__ out,
    float* __restrict__ sbl, float* __restrict__ sbr) {
  const int u = blockIdx.x, b = blockIdx.y;
  const int tA = 2 * u, tB = tA + 1;
  const int btA = b * T_LEN + tA, btB = btA + 1;
  const int j = threadIdx.x;
  __shared__ float2 WlA[1280];
  __shared__ float2 WlB[1280];
  __shared__ float2 Tws[1020];
  for (int e = j; e < 1020; e += 256) Tws[e] = twg[e];

  const float* zb = z + b * 256000;
  float f0A = 0.f, fS, f1B = 0.f;
  {
    int zi0 = tA * 256 + j - 255;
    f0A = (zi0 >= 0) ? zb[zi0] : 0.f;
    fS = zb[tA * 256 + j + 1];
    int zi2 = tB * 256 + j + 1;
    f1B = (zi2 < 256000) ? zb[zi2] : 0.f;
  }
  float c1A = 0.f, c2A = 0.f, c1B = 0.f, c2B = 0.f;
  if (j >= 145) {
    int mA = btA * 224 + (j - 145), mB = btB * 224 + (j - 145);
    c1A = (Pb[mA] + Pb[mA + PSTRIDE]) + (Pb[mA + 2 * PSTRIDE] + Pb[mA + 3 * PSTRIDE]);
    c1B = (Pb[mB] + Pb[mB + PSTRIDE]) + (Pb[mB + 2 * PSTRIDE] + Pb[mB + 3 * PSTRIDE]);
  }
  if (j < 111) {
    int mA = btA * 224 + (j + 111), mB = btB * 224 + (j + 111);
    c2A = (Pb[mA] + Pb[mA + PSTRIDE]) + (Pb[mA + 2 * PSTRIDE] + Pb[mA + 3 * PSTRIDE]);
    c2B = (Pb[mB] + Pb[mB + PSTRIDE]) + (Pb[mB + 2 * PSTRIDE] + Pb[mB + 3 * PSTRIDE]);
  }
  __syncthreads();

  {
    float2 e1 = Tws[j], e2 = Tws[256 + j], e3 = Tws[512 + j];
    const float2 w1 = make_float2(e1.x, -e1.y);
    const float2 w2 = make_float2(e2.x, -e2.y);
    const float2 w3 = make_float2(e3.x, -e3.y);
    {
      float2 t0 = make_float2(c2A, f0A);
      float2 t1 = make_float2(-c2A, f0A);
      float2 t2 = make_float2(c1A, fS);
      float2 t3 = make_float2(fS, -c1A);
      WlA[LIDX(j)]       = cadd(t0, t2);
      WlA[LIDX(j + 256)] = cmul(cadd(t1, t3), w1);
      WlA[LIDX(j + 512)] = cmul(csub(t0, t2), w2);
      WlA[LIDX(j + 768)] = cmul(csub(t1, t3), w3);
    }
    {
      float2 t0 = make_float2(c2B, fS);
      float2 t1 = make_float2(-c2B, fS);
      float2 t2 = make_float2(c1B, f1B);
      float2 t3 = make_float2(f1B, -c1B);
      WlB[LIDX(j)]       = cadd(t0, t2);
      WlB[LIDX(j + 256)] = cmul(cadd(t1, t3), w1);
      WlB[LIDX(j + 512)] = cmul(csub(t0, t2), w2);
      WlB[LIDX(j + 768)] = cmul(csub(t1, t3), w3);
    }
  }
  __syncthreads();

  fwd_stage2<64, 768>(WlA, WlB, Tws, j);  __syncthreads();
  fwd_stage2<16, 960>(WlA, WlB, Tws, j);  __syncthreads();
  fwd_stage2<4, 1008>(WlA, WlB, Tws, j);  __syncthreads();

  const int base = 4 * j;
  float2 XA[4], XB[4];
  {
    float2 u0 = WlA[LIDX(base)], u1 = WlA[LIDX(base + 1)];
    float2 u2 = WlA[LIDX(base + 2)], u3 = WlA[LIDX(base + 3)];
    float2 t0 = cadd(u0, u2), t1 = csub(u0, u2), t2 = cadd(u1, u3), bd = csub(u1, u3);
    float2 t3 = make_float2(bd.y, -bd.x);
    XA[0] = cadd(t0, t2); XA[1] = cadd(t1, t3); XA[2] = csub(t0, t2); XA[3] = csub(t1, t3);
  }
  {
    float2 u0 = WlB[LIDX(base)], u1 = WlB[LIDX(base + 1)];
    float2 u2 = WlB[LIDX(base + 2)], u3 = WlB[LIDX(base + 3)];
    float2 t0 = cadd(u0, u2), t1 = csub(u0, u2), t2 = cadd(u1, u3), bd = csub(u1, u3);
    float2 t3 = make_float2(bd.y, -bd.x);
    XB[0] = cadd(t0, t2); XB[1] = cadd(t1, t3); XB[2] = csub(t0, t2); XB[3] = csub(t1, t3);
  }
#pragma unroll
  for (int q = 0; q < 4; ++q) { WlA[LIDX(base + q)] = XA[q]; WlB[LIDX(base + q)] = XB[q]; }
  __syncthreads();

  const int r0 = rev4d(j);
  const bool self0 = (r0 == 0);
  const int jp = self0 ? 0 : rev4d((256 - r0) & 255);
  float2 PA[4], PB[4];
#pragma unroll
  for (int q = 0; q < 4; ++q) { PA[q] = WlA[LIDX(4 * jp + q)]; PB[q] = WlB[LIDX(4 * jp + q)]; }
  float2 Z[4];
#pragma unroll
  for (int q = 0; q < 4; ++q) {
    float2 SA, SB;
    {
      float2 A = XA[q];
      float2 Bc = self0 ? PA[(4 - q) & 3] : PA[3 - q];
      float2 Y = make_float2(0.5f * (A.x + Bc.x), 0.5f * (A.y - Bc.y));
      float2 F = make_float2(0.5f * (A.y + Bc.y), -0.5f * (A.x - Bc.x));
      float mag = __expf(Y.x * 2.30258509299404568402f);
      float sy, cy;
      __sincosf(Y.y, &sy, &cy);
      float gr = mag * cy, gi = mag * sy;
      SA = make_float2(fmaf(F.x, gr, F.y * gi), fmaf(F.x, gi, -(F.y * gr)));
    }
    {
      float2 A = XB[q];
      float2 Bc = self0 ? PB[(4 - q) & 3] : PB[3 - q];
      float2 Y = make_float2(0.5f * (A.x + Bc.x), 0.5f * (A.y - Bc.y));
      float2 F = make_float2(0.5f * (A.y + Bc.y), -0.5f * (A.x - Bc.x));
      float mag = __expf(Y.x * 2.30258509299404568402f);
      float sy, cy;
      __sincosf(Y.y, &sy, &cy);
      float gr = mag * cy, gi = mag * sy;
      SB = make_float2(fmaf(F.x, gr, F.y * gi), fmaf(F.x, gi, -(F.y * gr)));
    }
    Z[q] = make_float2(SA.x - SB.y, SA.y + SB.x);   // S_A + i*S_B
  }
  __syncthreads();

  {
    float2 t0 = cadd(Z[0], Z[2]), t1 = csub(Z[0], Z[2]), t2 = cadd(Z[1], Z[3]), bd = csub(Z[1], Z[3]);
    float2 t3 = make_float2(-bd.y, bd.x);
    WlA[LIDX(base)]     = cadd(t0, t2);
    WlA[LIDX(base + 1)] = cadd(t1, t3);
    WlA[LIDX(base + 2)] = csub(t0, t2);
    WlA[LIDX(base + 3)] = csub(t1, t3);
  }
  __syncthreads();

  inv_stage_t<4, 1008>(WlA, Tws, j);  __syncthreads();
  inv_stage_t<16, 960>(WlA, Tws, j);  __syncthreads();
  inv_stage_t<64, 768>(WlA, Tws, j);  __syncthreads();

  {
    float2 w1 = Tws[j], w2 = Tws[256 + j], w3 = Tws[512 + j];
    float2 a = WlA[LIDX(j)];
    float2 bb = cmul(WlA[LIDX(j + 256)], w1);
    float2 cc = cmul(WlA[LIDX(j + 512)], w2);
    float2 d = cmul(WlA[LIDX(j + 768)], w3);
    float2 t0 = cadd(a, cc), t1 = csub(a, cc), t2 = cadd(bb, d), bd = csub(bb, d);
    float2 t3 = make_float2(-bd.y, bd.x);
    float2 Cj    = cadd(t0, t2);   // C[j]     -> corr n1 = 511-j (r-part)
    float2 Cj256 = cadd(t1, t3);   // C[j+256] -> corr n2 = 255-j (l-part)
    int n1 = 511 - j, n2 = 255 - j;
    float wn1 = wing[n1], wn2 = wing[n2];
    float vA_l = Cj256.x * wn2;                 // even row tA contribution (l)
    float vAB  = Cj.x * wn1 + Cj256.y * wn2;    // odd row tB: A.r + B.l (owned)
    float vB_r = Cj.y * wn1;                    // even row tB+1 contribution (r)
    out[(b * T_LEN + tB) * 256 + n2] = vAB;
    int su = (b * 500 + u) * 256 + n2;
    sbl[su] = vA_l;
    sbr[su] = vB_r;
  }
}

// ---- even rows: out[b, 2u, n] = l(2u) + r(2u-1 mod 1000) ---------------------
__global__ __launch_bounds__(256) void k_even(const float* __restrict__ sbl,
    const float* __restrict__ sbr, float* __restrict__ out) {
  int idx = blockIdx.x * 256 + threadIdx.x;   // 1,024,000
  int n = idx & 255;
  int bu = idx >> 8;                          // b*500 + u
  int u = bu % 500, b = bu / 500;
  int up = (u == 0) ? 499 : u - 1;
  out[(b * T_LEN + 2 * u) * 256 + n] = sbl[idx] + sbr[(b * 500 + up) * 256 + n];
}

extern "C" void kernel_launch(void* const* d_in, const int* in_sizes, int n_in,
                              void* d_out, int out_size, void* d_ws, size_t ws_size,
                              hipStream_t stream) {
  const float* x  = (const float*)d_in[0];
  const float* z  = (const float*)d_in[1];
  const float* W1 = (const float*)d_in[2];
  const float* b1 = (const float*)d_in[3];
  const float* W2 = (const float*)d_in[4];
  const float* b2 = (const float*)d_in[5];
  const float* W3 = (const float*)d_in[6];
  const float* b3 = (const float*)d_in[7];
  const float* W4 = (const float*)d_in[8];
  const float* b4 = (const float*)d_in[9];

  float* ws   = (float*)d_ws;
  __hip_bfloat16* h3bf = (__hip_bfloat16*)ws;              // 1,024,000 f32 slots
  float* Pb   = ws + 1024000;            // 4 x 1,792,000 = 7,168,000
  float* sbl  = ws + 8192000;            // 1,024,000 (aliased: h1 fp16 before fft)
  float* sbr  = ws + 9216000;            // 1,024,000 (aliased: h2 fp16 before fft)
  _Float16* W1p = (_Float16*)(ws + 10240000);              // 73,728 halves
  _Float16* W2p = (_Float16*)(ws + 10301440);              // 24,576 halves
  _Float16* W3p = (_Float16*)(ws + 10326016);              // 24,576 halves
  __hip_bfloat16* Wc = (__hip_bfloat16*)(ws + 10350592);   // 98,304 f32 slots
  float2* twTab = (float2*)(ws + 10448896);                // 1020 float2
  float* winTab = ws + 10450944;                           // 512
  _Float16* xf16 = (_Float16*)(ws + 10451456);             // 768,000 halves
  _Float16* h1f = (_Float16*)sbl;                          // dead before fft writes sbl
  _Float16* h2f = (_Float16*)sbr;                          // dead before fft writes sbr
  float* out = (float*)d_out;

  dim3 blk(256);
  k_prep<<<4254, blk, 0, stream>>>(x, W1, W2, W3, W4, xf16, W1p, W2p, W3p,
                                   Wc, twTab, winTab);

  dim3 gc(32, B_N, 2);             // 32 M-tiles x 8 batches x 2 N-halves
  k_cgemm<9, false, 96, 104, false><<<gc, blk, 0, stream>>>(xf16, W1p, b1, (void*)h1f);
  k_cgemm<3, true, 256, 136, false><<<gc, blk, 0, stream>>>(h1f, W2p, b2, (void*)h2f);
  k_cgemm<3, true, 256, 136, true><<<gc, blk, 0, stream>>>(h2f, W3p, b3, (void*)h3bf);
  dim3 g4(16, B_N, 4);
  k_conv4m<<<g4, blk, 0, stream>>>(h3bf, Wc, b4, Pb);
  dim3 gf(T_LEN / 2, B_N);         // (500, 8)
  k_fft<<<gf, blk, 0, stream>>>(Pb, z, twTab, winTab, out, sbl, sbr);
  k_even<<<4000, blk, 0, stream>>>(sbl, sbr, out);
}

// Round 7
// 150.407 us; speedup vs baseline: 1.3824x; 1.0505x over previous
//
#include <hip/hip_runtime.h>
#include <hip/hip_bf16.h>

#define T_LEN 1000
#define B_N 8
#define IN_CH 80
#define CONV_CH 256
#define CCEP_N 222

typedef short s8v __attribute__((ext_vector_type(8)));      // 8 bf16 (4 VGPRs)
typedef _Float16 h8v __attribute__((ext_vector_type(8)));   // 8 fp16 (4 VGPRs)
typedef float f16v __attribute__((ext_vector_type(16)));    // MFMA 32x32 acc

#define TWO_PI 6.28318530717958647692f

// ===================== fused prep kernel (weights + tables) ===================
// [0,288): W1p [9][256][32] fp16, k = chg*32+kloc in [0,288), kappa=k/96, i=k%96
//          (i>=80 zero-padded);
// [288,384): W2p [3][256][32], k in [0,96), kappa=k>>5, iloc=k&31;
// [384,480): W3p same; [480,1248): Wc (conv4 bf16, /quef fused);
// [1248,1254): twiddle (1020 float2) + window (512).
__global__ __launch_bounds__(256) void k_prep(
    const float* __restrict__ W1, const float* __restrict__ W2,
    const float* __restrict__ W3, const float* __restrict__ W4,
    _Float16* __restrict__ W1p, _Float16* __restrict__ W2p,
    _Float16* __restrict__ W3p,
    __hip_bfloat16* __restrict__ Wc, float2* __restrict__ twTab,
    float* __restrict__ winTab) {
  const int bid = blockIdx.x, tid = threadIdx.x;
  if (bid < 288) {
    int e = bid * 256 + tid;                 // 73728 = 9*8192
    int kloc = e & 31, n = (e >> 5) & 255, chg = e >> 13;
    int k = chg * 32 + kloc;
    int kappa = k / 96, i = k - kappa * 96;
    W1p[e] = (i < IN_CH) ? (_Float16)W1[n * 240 + i * 3 + kappa] : (_Float16)0.f;
  } else if (bid < 384) {
    int e = (bid - 288) * 256 + tid;         // 24576 = 3*8192
    int kloc = e & 31, n = (e >> 5) & 255, chg = e >> 13;
    int k = chg * 32 + kloc;
    int kappa = k >> 5, iloc = k & 31;
    W2p[e] = (_Float16)W2[n * 96 + iloc * 3 + kappa];
  } else if (bid < 480) {
    int e = (bid - 384) * 256 + tid;
    int kloc = e & 31, n = (e >> 5) & 255, chg = e >> 13;
    int k = chg * 32 + kloc;
    int kappa = k >> 5, iloc = k & 31;
    W3p[e] = (_Float16)W3[n * 96 + iloc * 3 + kappa];
  } else if (bid < 1248) {
    int e = (bid - 480) * 256 + tid;         // 196608
    int kloc = e & 31, n = (e >> 5) & 255, chg = e >> 13;
    int kp = chg * 32 + kloc;
    int kappa = kp >> 8, i = kp & 255;
    float v = 0.f;
    if (n < CCEP_N) {
      float invq = 1.f / (float)((n < 111) ? (111 - n) : (n - 110));
      v = W4[n * 768 + i * 3 + kappa] * invq;
    }
    Wc[e] = __float2bfloat16(v);
  } else {
    int e = (bid - 1248) * 256 + tid;        // 0..1535
    if (e < 1020) {
      int Q, off;
      if (e < 768)       { Q = 256; off = 0; }
      else if (e < 960)  { Q = 64;  off = 768; }
      else if (e < 1008) { Q = 16;  off = 960; }
      else               { Q = 4;   off = 1008; }
      int rem = e - off;
      int r = rem / Q, pos = rem - r * Q;
      float ang = (TWO_PI * (float)((r + 1) * pos)) / (float)(4 * Q);
      float s, c;
      sincosf(ang, &s, &c);
      twTab[e] = make_float2(c, s);
    } else if (e < 1532) {
      int n = e - 1020;
      winTab[n] = (0.5f - 0.5f * cosf(TWO_PI * (float)n / 512.f)) * (1.f / 1024.f);
    }
  }
}

// ===== conv1-3 FULLY FUSED as MFMA fp16 GEMMs, h1/h2 in LDS ===================
// Block: 256 thr = 4 waves; 32 output t's (t0=mb*32) x 128 ch (z*128); wave w
// owns N-tile n0 = z*128 + w*32 (grouped layers: N-tile == in-group, closed).
// Halo via overlapping M-tiles: L1 computes h1 rows t0-2..t0+33 (tiles at
// offset 0 and +4, tile-b stores only row>=28); L2 computes h2 rows
// t0-1..t0+32 (offsets 0 and +2, tile-b stores row>=30); L3 one tile.
// Rows outside [0,T) zeroed at store (reference zero-pads each layer).
// x staged fp32->fp16 in-kernel. B double-buffered per 32-k chunk (pitch 48).
#define XP2 112   // xs pitch (halves): 224B, 4-way max bank aliasing
#define HP2 144   // h1s/h2s pitch: 288B, 4-way
#define BP2 48    // Bs pitch: 96B, 4-way

__global__ __launch_bounds__(256) void k_convfused(
    const float* __restrict__ x,
    const _Float16* __restrict__ W1p, const float* __restrict__ b1,
    const _Float16* __restrict__ W2p, const float* __restrict__ b2,
    const _Float16* __restrict__ W3p, const float* __restrict__ b3,
    __hip_bfloat16* __restrict__ out) {
  const int mb = blockIdx.x, b = blockIdx.y, z = blockIdx.z;
  const int t0 = mb * 32;
  const int tid = threadIdx.x;
  const int w = tid >> 6, lane = tid & 63;
  const int lm = lane & 31, half = lane >> 5;
  const int n0loc = w * 32;                  // wave's N-tile within block's 128
  const int c = z * 128 + n0loc + lm;        // global out channel

  __shared__ _Float16 xs[38 * XP2];          // rows t0-3 .. t0+34
  __shared__ _Float16 h1s[36 * HP2];         // idx = t-(t0-2), 0..35
  __shared__ _Float16 h2s[34 * HP2];         // idx = t-(t0-1), 0..33
  __shared__ _Float16 Bs[2][128 * BP2];

  // ---- stage x (fp32 -> fp16), zero-pad t outside [0,T) and ch >= 80 ----
  for (int e = tid; e < 38 * 96; e += 256) {
    int rr = e / 96, cc = e - rr * 96;
    int t = t0 - 3 + rr;
    float v = (cc < IN_CH && t >= 0 && t < T_LEN)
                  ? x[(b * T_LEN + t) * IN_CH + cc] : 0.f;
    xs[rr * XP2 + cc] = (_Float16)v;
  }
  {
    const _Float16* src = W1p + z * 4096;    // chg 0, this block's 128 n
    for (int e = tid; e < 512; e += 256) {
      int nl = e >> 2, c4 = e & 3;
      *(uint4*)(Bs[0] + nl * BP2 + c4 * 8) = *(const uint4*)(src + nl * 32 + c4 * 8);
    }
  }
  __syncthreads();

  // ---------- layer 1: K=288 (9 chgs), M-tiles at +0 and +4 ----------
  {
    f16v a0 = {}, a1 = {};
    for (int chg = 0; chg < 9; ++chg) {
      const int p = chg & 1;
      if (chg + 1 < 9) {
        const _Float16* src = W1p + (size_t)(chg + 1) * 8192 + z * 4096;
        for (int e = tid; e < 512; e += 256) {
          int nl = e >> 2, c4 = e & 3;
          *(uint4*)(Bs[p ^ 1] + nl * BP2 + c4 * 8) = *(const uint4*)(src + nl * 32 + c4 * 8);
        }
      }
#pragma unroll
      for (int s = 0; s < 2; ++s) {
        const int c16 = chg * 2 + s;
        const int kappa = c16 / 6;
        const int icol = (c16 - kappa * 6) * 16;
        h8v bf = *(const h8v*)(Bs[p] + (n0loc + lm) * BP2 + s * 16 + half * 8);
        h8v aa0 = *(const h8v*)(xs + (lm + kappa) * XP2 + icol + half * 8);
        h8v aa1 = *(const h8v*)(xs + (lm + kappa + 4) * XP2 + icol + half * 8);
        a0 = __builtin_amdgcn_mfma_f32_32x32x16_f16(aa0, bf, a0, 0, 0, 0);
        a1 = __builtin_amdgcn_mfma_f32_32x32x16_f16(aa1, bf, a1, 0, 0, 0);
      }
      __syncthreads();
    }
    const float bv = b1[c];
#pragma unroll
    for (int reg = 0; reg < 16; ++reg) {
      int row = (reg & 3) + 8 * (reg >> 2) + 4 * half;
      {
        int t = t0 - 2 + row;                // tile a -> idx row
        float v = (t >= 0 && t < T_LEN) ? fmaxf(a0[reg] + bv, 0.f) : 0.f;
        h1s[row * HP2 + n0loc + lm] = (_Float16)v;
      }
      if (row >= 28) {                       // tile b -> idx row+4 (32..35)
        int t = t0 + 2 + row;
        float v = (t >= 0 && t < T_LEN) ? fmaxf(a1[reg] + bv, 0.f) : 0.f;
        h1s[(row + 4) * HP2 + n0loc + lm] = (_Float16)v;
      }
    }
  }
  {
    const _Float16* src = W2p + z * 4096;    // Bs[0] free after loop barrier
    for (int e = tid; e < 512; e += 256) {
      int nl = e >> 2, c4 = e & 3;
      *(uint4*)(Bs[0] + nl * BP2 + c4 * 8) = *(const uint4*)(src + nl * 32 + c4 * 8);
    }
  }
  __syncthreads();

  // ---------- layer 2: K=96 grouped (3 chgs), M-tiles at +0 and +2 ----------
  {
    f16v a0 = {}, a1 = {};
    for (int chg = 0; chg < 3; ++chg) {
      const int p = chg & 1;
      if (chg + 1 < 3) {
        const _Float16* src = W2p + (size_t)(chg + 1) * 8192 + z * 4096;
        for (int e = tid; e < 512; e += 256) {
          int nl = e >> 2, c4 = e & 3;
          *(uint4*)(Bs[p ^ 1] + nl * BP2 + c4 * 8) = *(const uint4*)(src + nl * 32 + c4 * 8);
        }
      }
#pragma unroll
      for (int s = 0; s < 2; ++s) {
        const int c16 = chg * 2 + s;
        const int kappa = c16 >> 1;
        const int icol = n0loc + (c16 & 1) * 16;   // in-group == N-tile
        h8v bf = *(const h8v*)(Bs[p] + (n0loc + lm) * BP2 + s * 16 + half * 8);
        h8v aa0 = *(const h8v*)(h1s + (lm + kappa) * HP2 + icol + half * 8);
        h8v aa1 = *(const h8v*)(h1s + (lm + kappa + 2) * HP2 + icol + half * 8);
        a0 = __builtin_amdgcn_mfma_f32_32x32x16_f16(aa0, bf, a0, 0, 0, 0);
        a1 = __builtin_amdgcn_mfma_f32_32x32x16_f16(aa1, bf, a1, 0, 0, 0);
      }
      __syncthreads();
    }
    const float bv = b2[c];
#pragma unroll
    for (int reg = 0; reg < 16; ++reg) {
      int row = (reg & 3) + 8 * (reg >> 2) + 4 * half;
      {
        int t = t0 - 1 + row;                // tile a -> idx row
        float v = (t >= 0 && t < T_LEN) ? fmaxf(a0[reg] + bv, 0.f) : 0.f;
        h2s[row * HP2 + n0loc + lm] = (_Float16)v;
      }
      if (row >= 30) {                       // tile b -> idx row+2 (32..33)
        int t = t0 + 1 + row;
        float v = (t >= 0 && t < T_LEN) ? fmaxf(a1[reg] + bv, 0.f) : 0.f;
        h2s[(row + 2) * HP2 + n0loc + lm] = (_Float16)v;
      }
    }
  }
  {
    const _Float16* src = W3p + z * 4096;
    for (int e = tid; e < 512; e += 256) {
      int nl = e >> 2, c4 = e & 3;
      *(uint4*)(Bs[0] + nl * BP2 + c4 * 8) = *(const uint4*)(src + nl * 32 + c4 * 8);
    }
  }
  __syncthreads();

  // ---------- layer 3: K=96 grouped (3 chgs), one M-tile ----------
  {
    f16v a0 = {};
    for (int chg = 0; chg < 3; ++chg) {
      const int p = chg & 1;
      if (chg + 1 < 3) {
        const _Float16* src = W3p + (size_t)(chg + 1) * 8192 + z * 4096;
        for (int e = tid; e < 512; e += 256) {
          int nl = e >> 2, c4 = e & 3;
          *(uint4*)(Bs[p ^ 1] + nl * BP2 + c4 * 8) = *(const uint4*)(src + nl * 32 + c4 * 8);
        }
      }
#pragma unroll
      for (int s = 0; s < 2; ++s) {
        const int c16 = chg * 2 + s;
        const int kappa = c16 >> 1;
        const int icol = n0loc + (c16 & 1) * 16;
        h8v bf = *(const h8v*)(Bs[p] + (n0loc + lm) * BP2 + s * 16 + half * 8);
        h8v aa = *(const h8v*)(h2s + (lm + kappa) * HP2 + icol + half * 8);
        a0 = __builtin_amdgcn_mfma_f32_32x32x16_f16(aa, bf, a0, 0, 0, 0);
      }
      __syncthreads();
    }
    const float bv = b3[c];
#pragma unroll
    for (int reg = 0; reg < 16; ++reg) {
      int row = (reg & 3) + 8 * (reg >> 2) + 4 * half;
      int t = t0 + row;
      if (t < T_LEN)
        out[(size_t)(b * T_LEN + t) * CONV_CH + c] =
            __float2bfloat16(fmaxf(a0[reg] + bv, 0.f));
    }
  }
}

// ============ conv4 as MFMA GEMM, K-split x4: 512 blocks (2/CU) ===============
#define APITCH 264
#define BPITCH 40
#define PSTRIDE 1792000
__global__ __launch_bounds__(256) void k_conv4m(
    const __hip_bfloat16* __restrict__ h3, const __hip_bfloat16* __restrict__ Wc,
    const float* __restrict__ bias, float* __restrict__ Pbase) {
  const int mb = blockIdx.x, b = blockIdx.y, ks = blockIdx.z;
  float* __restrict__ P = Pbase + (size_t)ks * PSTRIDE;
  const int t0 = mb * 64;
  const int tid = threadIdx.x;
  const int w = tid >> 6, lane = tid & 63;
  const int wm = w >> 1, wn = w & 1;
  const int lm = lane & 31, half = lane >> 5;

  __shared__ short h3s[67 * APITCH];
  __shared__ short Bs[2][256 * BPITCH];

  const ushort* h3u = (const ushort*)h3;
  for (int g = tid; g < 67 * 64; g += 256) {
    int rr = g >> 6, c4 = g & 63;
    int t = t0 + rr - 1;
    uint2 v = make_uint2(0u, 0u);
    if (t >= 0 && t < T_LEN)
      v = *(const uint2*)(h3u + (b * T_LEN + t) * CONV_CH + c4 * 4);
    *(uint2*)(h3s + rr * APITCH + c4 * 4) = v;
  }

  const ushort* Wu = (const ushort*)(Wc) + (size_t)(ks * 6) * 8192;
#pragma unroll
  for (int it = 0; it < 4; ++it) {
    int idx = (it * 256 + tid) * 8;
    uint4 v = *(const uint4*)(Wu + idx);
    int n = idx >> 5, kloc = idx & 31;
    *(uint4*)(Bs[0] + n * BPITCH + kloc) = v;
  }
  __syncthreads();

  f16v acc0 = {}, acc1 = {}, acc2 = {}, acc3 = {};

  for (int ch = 0; ch < 6; ++ch) {
    const int p = ch & 1;
    if (ch < 5) {
      const ushort* src = Wu + (ch + 1) * 8192;
#pragma unroll
      for (int it = 0; it < 4; ++it) {
        int idx = (it * 256 + tid) * 8;
        uint4 v = *(const uint4*)(src + idx);
        int n = idx >> 5, kloc = idx & 31;
        *(uint4*)(Bs[p ^ 1] + n * BPITCH + kloc) = v;
      }
    }
#pragma unroll
    for (int s = 0; s < 2; ++s) {
      int k0 = ks * 192 + ch * 32 + s * 16;
      int kappa = k0 >> 8, i0 = k0 & 255;
      s8v a = *(const s8v*)(h3s + (wm * 32 + lm + kappa) * APITCH + i0 + half * 8);
      const short* bp = Bs[p] + (wn * 128 + lm) * BPITCH + s * 16 + half * 8;
      s8v b0 = *(const s8v*)(bp);
      s8v b1 = *(const s8v*)(bp + 32 * BPITCH);
      s8v b2 = *(const s8v*)(bp + 64 * BPITCH);
      s8v b3 = *(const s8v*)(bp + 96 * BPITCH);
      acc0 = __builtin_amdgcn_mfma_f32_32x32x16_bf16(a, b0, acc0, 0, 0, 0);
      acc1 = __builtin_amdgcn_mfma_f32_32x32x16_bf16(a, b1, acc1, 0, 0, 0);
      acc2 = __builtin_amdgcn_mfma_f32_32x32x16_bf16(a, b2, acc2, 0, 0, 0);
      acc3 = __builtin_amdgcn_mfma_f32_32x32x16_bf16(a, b3, acc3, 0, 0, 0);
    }
    __syncthreads();
  }

  const int col = lm;
#pragma unroll
  for (int nt = 0; nt < 4; ++nt) {
    int c = wn * 128 + nt * 32 + col;
    if (c >= CCEP_N) continue;
    float bq = 0.f;
    if (ks == 0) {
      float invq = 1.f / (float)((c < 111) ? (111 - c) : (c - 110));
      bq = bias[c] * invq;
    }
    const f16v* A = (nt == 0) ? &acc0 : (nt == 1) ? &acc1 : (nt == 2) ? &acc2 : &acc3;
#pragma unroll
    for (int reg = 0; reg < 16; ++reg) {
      int row = (reg & 3) + 8 * (reg >> 2) + 4 * half;
      int t = t0 + wm * 32 + row;
      if (t < T_LEN)
        P[(size_t)(b * T_LEN + t) * 224 + c] = (*A)[reg] + bq;
    }
  }
}

// ============================ fused FFT kernel (2 frames/block) ===============
// Frames tA=2u, tB=2u+1. Two packed forward FFTs (c + i*fr per frame); S_A, S_B
// Hermitian -> ONE inverse: Z = S_A + i*S_B, IFFT(Z) = C_A + i*C_B (both real).
// Odd rows stored directly; even-row contributions spilled to sbl/sbr; no atomics.
__device__ __forceinline__ float2 cmul(float2 a, float2 b) {
  return make_float2(fmaf(a.x, b.x, -(a.y * b.y)), fmaf(a.x, b.y, a.y * b.x));
}
__device__ __forceinline__ float2 cadd(float2 a, float2 b) { return make_float2(a.x + b.x, a.y + b.y); }
__device__ __forceinline__ float2 csub(float2 a, float2 b) { return make_float2(a.x - b.x, a.y - b.y); }

#define LIDX(i) ((i) + ((i) >> 2))

template <int Q, int OFF>
__device__ __forceinline__ void fwd_stage2(float2* __restrict__ A,
    float2* __restrict__ B, const float2* __restrict__ Tw, int j) {
  const int pos = j & (Q - 1);
  const int base = ((j - pos) << 2) + pos;
  float2 e1 = Tw[OFF + pos], e2 = Tw[OFF + Q + pos], e3 = Tw[OFF + 2 * Q + pos];
  const float2 w1 = make_float2(e1.x, -e1.y);
  const float2 w2 = make_float2(e2.x, -e2.y);
  const float2 w3 = make_float2(e3.x, -e3.y);
#pragma unroll
  for (int arr = 0; arr < 2; ++arr) {
    float2* X = arr ? B : A;
    float2 a = X[LIDX(base)], b = X[LIDX(base + Q)];
    float2 cc = X[LIDX(base + 2 * Q)], d = X[LIDX(base + 3 * Q)];
    float2 t0 = cadd(a, cc), t1 = csub(a, cc), t2 = cadd(b, d), bd = csub(b, d);
    float2 t3 = make_float2(bd.y, -bd.x);
    X[LIDX(base)]         = cadd(t0, t2);
    X[LIDX(base + Q)]     = cmul(cadd(t1, t3), w1);
    X[LIDX(base + 2 * Q)] = cmul(csub(t0, t2), w2);
    X[LIDX(base + 3 * Q)] = cmul(csub(t1, t3), w3);
  }
}

template <int Q, int OFF>
__device__ __forceinline__ void inv_stage_t(float2* __restrict__ X,
    const float2* __restrict__ Tw, int j) {
  const int pos = j & (Q - 1);
  const int base = ((j - pos) << 2) + pos;
  const float2 w1 = Tw[OFF + pos];
  const float2 w2 = Tw[OFF + Q + pos];
  const float2 w3 = Tw[OFF + 2 * Q + pos];
  float2 a = X[LIDX(base)];
  float2 b = cmul(X[LIDX(base + Q)], w1);
  float2 cc = cmul(X[LIDX(base + 2 * Q)], w2);
  float2 d = cmul(X[LIDX(base + 3 * Q)], w3);
  float2 t0 = cadd(a, cc), t1 = csub(a, cc), t2 = cadd(b, d), bd = csub(b, d);
  float2 t3 = make_float2(-bd.y, bd.x);
  X[LIDX(base)]         = cadd(t0, t2);
  X[LIDX(base + Q)]     = cadd(t1, t3);
  X[LIDX(base + 2 * Q)] = csub(t0, t2);
  X[LIDX(base + 3 * Q)] = csub(t1, t3);
}

__device__ __forceinline__ int rev4d(int v) {
  return ((v & 3) << 6) | (((v >> 2) & 3) << 4) | (((v >> 4) & 3) << 2) | ((v >> 6) & 3);
}

// grid (500, 8)
__global__ __launch_bounds__(256) void k_fft(const float* __restrict__ Pb,
    const float* __restrict__ z, const float2* __restrict__ twg,
    const float* __restrict__ wing, float* __restrict__ out,
    float* __restrict__ sbl, float* __restrict__ sbr) {
  const int u = blockIdx.x, b = blockIdx.y;
  const int tA = 2 * u, tB = tA + 1;
  const int btA = b * T_LEN + tA, btB = btA + 1;
  const int j = threadIdx.x;
  __shared__ float2 WlA[1280];
  __shared__ float2 WlB[1280];
  __shared__ float2 Tws[1020];
  for (int e = j; e < 1020; e += 256) Tws[e] = twg[e];

  const float* zb = z + b * 256000;
  float f0A = 0.f, fS, f1B = 0.f;
  {
    int zi0 = tA * 256 + j - 255;
    f0A = (zi0 >= 0) ? zb[zi0] : 0.f;
    fS = zb[tA * 256 + j + 1];
    int zi2 = tB * 256 + j + 1;
    f1B = (zi2 < 256000) ? zb[zi2] : 0.f;
  }
  float c1A = 0.f, c2A = 0.f, c1B = 0.f, c2B = 0.f;
  if (j >= 145) {
    int mA = btA * 224 + (j - 145), mB = btB * 224 + (j - 145);
    c1A = (Pb[mA] + Pb[mA + PSTRIDE]) + (Pb[mA + 2 * PSTRIDE] + Pb[mA + 3 * PSTRIDE]);
    c1B = (Pb[mB] + Pb[mB + PSTRIDE]) + (Pb[mB + 2 * PSTRIDE] + Pb[mB + 3 * PSTRIDE]);
  }
  if (j < 111) {
    int mA = btA * 224 + (j + 111), mB = btB * 224 + (j + 111);
    c2A = (Pb[mA] + Pb[mA + PSTRIDE]) + (Pb[mA + 2 * PSTRIDE] + Pb[mA + 3 * PSTRIDE]);
    c2B = (Pb[mB] + Pb[mB + PSTRIDE]) + (Pb[mB + 2 * PSTRIDE] + Pb[mB + 3 * PSTRIDE]);
  }
  __syncthreads();

  {
    float2 e1 = Tws[j], e2 = Tws[256 + j], e3 = Tws[512 + j];
    const float2 w1 = make_float2(e1.x, -e1.y);
    const float2 w2 = make_float2(e2.x, -e2.y);
    const float2 w3 = make_float2(e3.x, -e3.y);
    {
      float2 t0 = make_float2(c2A, f0A);
      float2 t1 = make_float2(-c2A, f0A);
      float2 t2 = make_float2(c1A, fS);
      float2 t3 = make_float2(fS, -c1A);
      WlA[LIDX(j)]       = cadd(t0, t2);
      WlA[LIDX(j + 256)] = cmul(cadd(t1, t3), w1);
      WlA[LIDX(j + 512)] = cmul(csub(t0, t2), w2);
      WlA[LIDX(j + 768)] = cmul(csub(t1, t3), w3);
    }
    {
      float2 t0 = make_float2(c2B, fS);
      float2 t1 = make_float2(-c2B, fS);
      float2 t2 = make_float2(c1B, f1B);
      float2 t3 = make_float2(f1B, -c1B);
      WlB[LIDX(j)]       = cadd(t0, t2);
      WlB[LIDX(j + 256)] = cmul(cadd(t1, t3), w1);
      WlB[LIDX(j + 512)] = cmul(csub(t0, t2), w2);
      WlB[LIDX(j + 768)] = cmul(csub(t1, t3), w3);
    }
  }
  __syncthreads();

  fwd_stage2<64, 768>(WlA, WlB, Tws, j);  __syncthreads();
  fwd_stage2<16, 960>(WlA, WlB, Tws, j);  __syncthreads();
  fwd_stage2<4, 1008>(WlA, WlB, Tws, j);  __syncthreads();

  const int base = 4 * j;
  float2 XA[4], XB[4];
  {
    float2 u0 = WlA[LIDX(base)], u1 = WlA[LIDX(base + 1)];
    float2 u2 = WlA[LIDX(base + 2)], u3 = WlA[LIDX(base + 3)];
    float2 t0 = cadd(u0, u2), t1 = csub(u0, u2), t2 = cadd(u1, u3), bd = csub(u1, u3);
    float2 t3 = make_float2(bd.y, -bd.x);
    XA[0] = cadd(t0, t2); XA[1] = cadd(t1, t3); XA[2] = csub(t0, t2); XA[3] = csub(t1, t3);
  }
  {
    float2 u0 = WlB[LIDX(base)], u1 = WlB[LIDX(base + 1)];
    float2 u2 = WlB[LIDX(base + 2)], u3 = WlB[LIDX(base + 3)];
    float2 t0 = cadd(u0, u2), t1 = csub(u0, u2), t2 = cadd(u1, u3), bd = csub(u1, u3);
    float2 t3 = make_float2(bd.y, -bd.x);
    XB[0] = cadd(t0, t2); XB[1] = cadd(t1, t3); XB[2] = csub(t0, t2); XB[3] = csub(t1, t3);
  }
#pragma unroll
  for (int q = 0; q < 4; ++q) { WlA[LIDX(base + q)] = XA[q]; WlB[LIDX(base + q)] = XB[q]; }
  __syncthreads();

  const int r0 = rev4d(j);
  const bool self0 = (r0 == 0);
  const int jp = self0 ? 0 : rev4d((256 - r0) & 255);
  float2 PA[4], PB[4];
#pragma unroll
  for (int q = 0; q < 4; ++q) { PA[q] = WlA[LIDX(4 * jp + q)]; PB[q] = WlB[LIDX(4 * jp + q)]; }
  float2 Z[4];
#pragma unroll
  for (int q = 0; q < 4; ++q) {
    float2 SA, SB;
    {
      float2 A = XA[q];
      float2 Bc = self0 ? PA[(4 - q) & 3] : PA[3 - q];
      float2 Y = make_float2(0.5f * (A.x + Bc.x), 0.5f * (A.y - Bc.y));
      float2 F = make_float2(0.5f * (A.y + Bc.y), -0.5f * (A.x - Bc.x));
      float mag = __expf(Y.x * 2.30258509299404568402f);
      float sy, cy;
      __sincosf(Y.y, &sy, &cy);
      float gr = mag * cy, gi = mag * sy;
      SA = make_float2(fmaf(F.x, gr, F.y * gi), fmaf(F.x, gi, -(F.y * gr)));
    }
    {
      float2 A = XB[q];
      float2 Bc = self0 ? PB[(4 - q) & 3] : PB[3 - q];
      float2 Y = make_float2(0.5f * (A.x + Bc.x), 0.5f * (A.y - Bc.y));
      float2 F = make_float2(0.5f * (A.y + Bc.y), -0.5f * (A.x - Bc.x));
      float mag = __expf(Y.x * 2.30258509299404568402f);
      float sy, cy;
      __sincosf(Y.y, &sy, &cy);
      float gr = mag * cy, gi = mag * sy;
      SB = make_float2(fmaf(F.x, gr, F.y * gi), fmaf(F.x, gi, -(F.y * gr)));
    }
    Z[q] = make_float2(SA.x - SB.y, SA.y + SB.x);   // S_A + i*S_B
  }
  __syncthreads();

  {
    float2 t0 = cadd(Z[0], Z[2]), t1 = csub(Z[0], Z[2]), t2 = cadd(Z[1], Z[3]), bd = csub(Z[1], Z[3]);
    float2 t3 = make_float2(-bd.y, bd.x);
    WlA[LIDX(base)]     = cadd(t0, t2);
    WlA[LIDX(base + 1)] = cadd(t1, t3);
    WlA[LIDX(base + 2)] = csub(t0, t2);
    WlA[LIDX(base + 3)] = csub(t1, t3);
  }
  __syncthreads();

  inv_stage_t<4, 1008>(WlA, Tws, j);  __syncthreads();
  inv_stage_t<16, 960>(WlA, Tws, j);  __syncthreads();
  inv_stage_t<64, 768>(WlA, Tws, j);  __syncthreads();

  {
    float2 w1 = Tws[j], w2 = Tws[256 + j], w3 = Tws[512 + j];
    float2 a = WlA[LIDX(j)];
    float2 bb = cmul(WlA[LIDX(j + 256)], w1);
    float2 cc = cmul(WlA[LIDX(j + 512)], w2);
    float2 d = cmul(WlA[LIDX(j + 768)], w3);
    float2 t0 = cadd(a, cc), t1 = csub(a, cc), t2 = cadd(bb, d), bd = csub(bb, d);
    float2 t3 = make_float2(-bd.y, bd.x);
    float2 Cj    = cadd(t0, t2);   // C[j]     -> corr n1 = 511-j (r-part)
    float2 Cj256 = cadd(t1, t3);   // C[j+256] -> corr n2 = 255-j (l-part)
    int n1 = 511 - j, n2 = 255 - j;
    float wn1 = wing[n1], wn2 = wing[n2];
    float vA_l = Cj256.x * wn2;                 // even row tA contribution (l)
    float vAB  = Cj.x * wn1 + Cj256.y * wn2;    // odd row tB: A.r + B.l (owned)
    float vB_r = Cj.y * wn1;                    // even row tB+1 contribution (r)
    out[(b * T_LEN + tB) * 256 + n2] = vAB;
    int su = (b * 500 + u) * 256 + n2;
    sbl[su] = vA_l;
    sbr[su] = vB_r;
  }
}

// ---- even rows: out[b, 2u, n] = l(2u) + r(2u-1 mod 1000) ---------------------
__global__ __launch_bounds__(256) void k_even(const float* __restrict__ sbl,
    const float* __restrict__ sbr, float* __restrict__ out) {
  int idx = blockIdx.x * 256 + threadIdx.x;   // 1,024,000
  int n = idx & 255;
  int bu = idx >> 8;                          // b*500 + u
  int u = bu % 500, b = bu / 500;
  int up = (u == 0) ? 499 : u - 1;
  out[(b * T_LEN + 2 * u) * 256 + n] = sbl[idx] + sbr[(b * 500 + up) * 256 + n];
}

extern "C" void kernel_launch(void* const* d_in, const int* in_sizes, int n_in,
                              void* d_out, int out_size, void* d_ws, size_t ws_size,
                              hipStream_t stream) {
  const float* x  = (const float*)d_in[0];
  const float* z  = (const float*)d_in[1];
  const float* W1 = (const float*)d_in[2];
  const float* b1 = (const float*)d_in[3];
  const float* W2 = (const float*)d_in[4];
  const float* b2 = (const float*)d_in[5];
  const float* W3 = (const float*)d_in[6];
  const float* b3 = (const float*)d_in[7];
  const float* W4 = (const float*)d_in[8];
  const float* b4 = (const float*)d_in[9];

  float* ws   = (float*)d_ws;
  __hip_bfloat16* h3bf = (__hip_bfloat16*)ws;              // 1,024,000 f32 slots
  float* Pb   = ws + 1024000;            // 4 x 1,792,000 = 7,168,000
  float* sbl  = ws + 8192000;            // 1,024,000
  float* sbr  = ws + 9216000;            // 1,024,000
  _Float16* W1p = (_Float16*)(ws + 10240000);              // 73,728 halves
  _Float16* W2p = (_Float16*)(ws + 10301440);              // 24,576 halves
  _Float16* W3p = (_Float16*)(ws + 10326016);              // 24,576 halves
  __hip_bfloat16* Wc = (__hip_bfloat16*)(ws + 10350592);   // 98,304 f32 slots
  float2* twTab = (float2*)(ws + 10448896);                // 1020 float2
  float* winTab = ws + 10450944;                           // 512
  float* out = (float*)d_out;

  dim3 blk(256);
  k_prep<<<1254, blk, 0, stream>>>(W1, W2, W3, W4, W1p, W2p, W3p,
                                   Wc, twTab, winTab);

  dim3 gc(32, B_N, 2);             // 32 M-tiles x 8 batches x 2 N-halves
  k_convfused<<<gc, blk, 0, stream>>>(x, W1p, b1, W2p, b2, W3p, b3, h3bf);
  dim3 g4(16, B_N, 4);
  k_conv4m<<<g4, blk, 0, stream>>>(h3bf, Wc, b4, Pb);
  dim3 gf(T_LEN / 2, B_N);         // (500, 8)
  k_fft<<<gf, blk, 0, stream>>>(Pb, z, twTab, winTab, out, sbl, sbr);
  k_even<<<4000, blk, 0, stream>>>(sbl, sbr, out);
}